// Round 6
// baseline (290.008 us; speedup 1.0000x reference)
//
#include <hip/hip_runtime.h>
#include <hip/hip_bf16.h>
#include <math.h>

typedef __hip_bfloat16 bf16;
typedef float4 f4;

#define B 32
#define V 64
#define F 128
#define NL 128
#define H 8
#define DH 16
#define LEN_PRED 30

// ---- f32 workspace layout (element offsets) ----
#define OFF_EMBW 0
#define OFF_EMBB 768
#define OFF_B1   896
#define OFF_B2   1024
#define OFF_BO   1152
#define WCP_T    1216
#define WCSA_T   17600
#define WCLA_T   33984
#define W1_T     50368
#define W2_T     66752
#define WO_T     83136
#define OFF_FEAT 87744
#define OFF_OSA  349888
#define OFF_BAR  612032      // 2 ints: {count, generation}

struct InPtrs { const void* p[23]; };

__device__ __forceinline__ float dot4(f4 a, f4 b) {
    return a.x * b.x + a.y * b.y + a.z * b.z + a.w * b.w;
}

// dtype detect: f32 read as u16 pairs has wild exponents in mantissa halves;
// bf16 N(0,1) never does. Uniform across all waves.
__device__ __forceinline__ int detect_f32(const void* lanesraw, int t) {
    const unsigned short* u = (const unsigned short*)lanesraw;
    int lane = t & 63;
    int wild = 0;
    for (int j = 0; j < 4; j++) {
        int e = (u[lane * 4 + j] >> 7) & 0xFF;
        if (e != 0 && (e < 90 || e > 164)) wild++;
    }
    unsigned long long m = __ballot(wild > 0);
    return (__popcll(m) >= 16) ? 1 : 0;
}

__device__ __forceinline__ float ldin(const void* p, int i, int fl) {
    return fl ? ((const float*)p)[i] : __bfloat162float(((const bf16*)p)[i]);
}

// grid-wide barrier: all 256 blocks co-resident (1 block/CU by LDS).
__device__ __forceinline__ void grid_bar(int* bar) {
    __syncthreads();
    if (threadIdx.x == 0) {
        __threadfence();   // agent-scope release of this block's phase writes
        int g = __hip_atomic_load(bar + 1, __ATOMIC_RELAXED, __HIP_MEMORY_SCOPE_AGENT);
        int v = __hip_atomic_fetch_add(bar, 1, __ATOMIC_ACQ_REL, __HIP_MEMORY_SCOPE_AGENT);
        if (v == (int)gridDim.x - 1) {
            __hip_atomic_store(bar, 0, __ATOMIC_RELAXED, __HIP_MEMORY_SCOPE_AGENT);
            __hip_atomic_fetch_add(bar + 1, 1, __ATOMIC_ACQ_REL, __HIP_MEMORY_SCOPE_AGENT);
        } else {
            while (__hip_atomic_load(bar + 1, __ATOMIC_ACQUIRE, __HIP_MEMORY_SCOPE_AGENT) == g)
                __builtin_amdgcn_s_sleep(2);
        }
        __threadfence();   // acquire: invalidate L1/L2 before next phase reads
    }
    __syncthreads();
}

// ---------------- prep: vec copies + 6 weight transposes (blocks 0..10) ----------------
__device__ void phase_prep(float* sm, const InPtrs& ptrs, int fl, float* ws, int seg) {
    const int srci[11] = {3, 4, 18, 20, 22, 8, 12, 16, 17, 19, 21};
    const int szs[11]  = {768, 128, 128, 128, 36, 16384, 16384, 16384, 16384, 16384, 4608};
    const int dsto[11] = {OFF_EMBW, OFF_EMBB, OFF_B1, OFF_B2, OFF_BO,
                          WCP_T, WCSA_T, WCLA_T, W1_T, W2_T, WO_T};
    const int Otab[11] = {0, 0, 0, 0, 0, 128, 128, 128, 128, 128, 36};
    int t = threadIdx.x;
    int n = szs[seg], O = Otab[seg];
    const void* src = ptrs.p[srci[seg]];
    if (O == 0) {
        for (int i = t; i < n; i += 512) ws[dsto[seg] + i] = ldin(src, i, fl);
        return;
    }
    float* tile = sm;                       // 128*129 = 16512 floats
    for (int i = t; i < n; i += 512) {
        int o = i >> 7, k = i & 127;
        tile[o * 129 + k] = ldin(src, i, fl);
    }
    __syncthreads();
    float* dst = ws + dsto[seg];
    for (int j = t; j < n; j += 512) {
        int k = j / O, o = j - k * O;
        dst[j] = tile[o * 129 + k];
    }
}

// ---------------- lane attention (past & fut), per (b,h) ----------------
__device__ void phase_attn_lane(float* sm, const void* rwq, const void* rwk,
        const void* rwv, const void* rlanes, const void* rinp,
        const void* rembw, const void* rembb, const float* xsrc, int use_emb,
        int b, int h, int fl, float* osa) {
    int t = threadIdx.x;
    float* ln   = sm;            // 128*68 (aliased by scores later)
    float* xs   = sm + 8704;     // 64*132
    float* wql  = sm + 17152;    // 16*132
    float* wkl  = sm + 19264;    // 16*68
    float* wvl  = sm + 20352;    // 16*68
    float* kh   = sm + 21440;    // 128*20
    float* vhT  = sm + 24000;    // 16*132
    float* qh   = sm + 26112;    // 64*20
    float* rsum = sm + 27392;    // 64
    float* in4  = sm + 27456;    // 256
    float* s    = ln;

    int lb = b * NL * 64;
    for (int i = t; i < NL * 64; i += 512)
        ln[(i >> 6) * 68 + (i & 63)] = ldin(rlanes, lb + i, fl);
    for (int i = t; i < 16 * 128; i += 512)
        wql[(i >> 7) * 132 + (i & 127)] = ldin(rwq, h * 2048 + i, fl);
    for (int i = t; i < 16 * 64; i += 512)
        wkl[(i >> 6) * 68 + (i & 63)] = ldin(rwk, h * 1024 + i, fl);
    for (int i = t; i < 16 * 64; i += 512)
        wvl[(i >> 6) * 68 + (i & 63)] = ldin(rwv, h * 1024 + i, fl);
    if (use_emb) {
        if (t < 64) {
            in4[t * 4 + 0] = ldin(rinp, ((b * 2 + 0) * 64 + t) * 20 + 18, fl);
            in4[t * 4 + 1] = ldin(rinp, ((b * 2 + 0) * 64 + t) * 20 + 19, fl);
            in4[t * 4 + 2] = ldin(rinp, ((b * 2 + 1) * 64 + t) * 20 + 18, fl);
            in4[t * 4 + 3] = ldin(rinp, ((b * 2 + 1) * 64 + t) * 20 + 19, fl);
        }
        __syncthreads();
        for (int i = t; i < 8192; i += 512) {
            int v = i >> 7, c = i & 127;
            xs[v * 132 + c] = ldin(rembb, c, fl)
                + in4[v * 4 + 0] * ldin(rembw, c * 6 + 0, fl)
                + in4[v * 4 + 1] * ldin(rembw, c * 6 + 1, fl)
                + in4[v * 4 + 2] * ldin(rembw, c * 6 + 3, fl)
                + in4[v * 4 + 3] * ldin(rembw, c * 6 + 4, fl);
        }
    } else {
        const float* fb = xsrc + b * V * F;
        for (int i = t; i < 8192; i += 512) xs[(i >> 7) * 132 + (i & 127)] = fb[i];
    }
    __syncthreads();

    // proj: t<256 -> K,V (8 out each per mat); t>=256 -> Q (4 out)
    if (t < 256) {
        int l0 = t >> 3, d0 = (t & 7) * 2;
        float ak[4][2] = {}, av[4][2] = {};
        for (int kk = 0; kk < 64; kk += 4) {
            f4 L[4], WK[2], WV[2];
            #pragma unroll
            for (int m = 0; m < 4; m++) L[m] = *(const f4*)&ln[(l0 + 32 * m) * 68 + kk];
            #pragma unroll
            for (int j = 0; j < 2; j++) {
                WK[j] = *(const f4*)&wkl[(d0 + j) * 68 + kk];
                WV[j] = *(const f4*)&wvl[(d0 + j) * 68 + kk];
            }
            #pragma unroll
            for (int m = 0; m < 4; m++)
                #pragma unroll
                for (int j = 0; j < 2; j++) {
                    ak[m][j] += dot4(L[m], WK[j]);
                    av[m][j] += dot4(L[m], WV[j]);
                }
        }
        #pragma unroll
        for (int m = 0; m < 4; m++)
            #pragma unroll
            for (int j = 0; j < 2; j++) {
                int l = l0 + 32 * m, d = d0 + j;
                kh[l * 20 + d] = ak[m][j];
                vhT[d * 132 + l] = av[m][j];
            }
    } else {
        int tt = t - 256, v = tt >> 2, d0 = (tt & 3) * 4;
        float aq[4] = {};
        for (int kk = 0; kk < 128; kk += 4) {
            f4 X = *(const f4*)&xs[v * 132 + kk];
            #pragma unroll
            for (int i2 = 0; i2 < 4; i2++)
                aq[i2] += dot4(X, *(const f4*)&wql[(d0 + i2) * 132 + kk]);
        }
        #pragma unroll
        for (int i2 = 0; i2 < 4; i2++) qh[v * 20 + d0 + i2] = aq[i2];
    }
    __syncthreads();

    // scores: all 512 thr, 4x4 tiles; writes into s (= dead ln region)
    {
        int v0 = t >> 5, l0 = t & 31;
        float sc[4][4] = {};
        #pragma unroll
        for (int kd = 0; kd < 16; kd += 4) {
            f4 Q[4], K4[4];
            #pragma unroll
            for (int m = 0; m < 4; m++) Q[m] = *(const f4*)&qh[(v0 + 16 * m) * 20 + kd];
            #pragma unroll
            for (int i2 = 0; i2 < 4; i2++) K4[i2] = *(const f4*)&kh[(l0 + 32 * i2) * 20 + kd];
            #pragma unroll
            for (int m = 0; m < 4; m++)
                #pragma unroll
                for (int i2 = 0; i2 < 4; i2++) sc[m][i2] += dot4(Q[m], K4[i2]);
        }
        #pragma unroll
        for (int m = 0; m < 4; m++)
            #pragma unroll
            for (int i2 = 0; i2 < 4; i2++)
                s[(v0 + 16 * m) * 132 + l0 + 32 * i2] = sc[m][i2] * 0.25f;
    }
    __syncthreads();

    {   // softmax: 8 lanes per row
        int v = t >> 3, j = t & 7;
        float* sr = s + v * 132;
        float m = -1e30f;
        for (int k = j; k < NL; k += 8) m = fmaxf(m, sr[k]);
        for (int off = 1; off < 8; off <<= 1) m = fmaxf(m, __shfl_xor(m, off));
        float sum = 0.f;
        for (int k = j; k < NL; k += 8) { float e = __expf(sr[k] - m); sr[k] = e; sum += e; }
        for (int off = 1; off < 8; off <<= 1) sum += __shfl_xor(sum, off);
        if (j == 0) rsum[v] = sum;
    }
    __syncthreads();

    // PV: 256 thr, 1v x 4d
    if (t < 256) {
        int v = t >> 2, d0 = (t & 3) * 4;
        float o4[4] = {};
        for (int ll = 0; ll < NL; ll += 4) {
            f4 S4 = *(const f4*)&s[v * 132 + ll];
            #pragma unroll
            for (int i2 = 0; i2 < 4; i2++)
                o4[i2] += dot4(S4, *(const f4*)&vhT[(d0 + i2) * 132 + ll]);
        }
        float* ob = osa + b * V * F + h * 16;
        float inv = 1.0f / rsum[v];
        #pragma unroll
        for (int i2 = 0; i2 < 4; i2++) ob[v * F + d0 + i2] = o4[i2] * inv;
    }
}

// ---------------- SelfAttentionFut, per (b,h) ----------------
__device__ void phase_saf(float* sm, const void* rwq, const void* rwk, const void* rwv,
                          const float* feat, int b, int h, int fl, float* osa) {
    int t = threadIdx.x;
    float* xs   = sm;            // 64*132
    float* wsl  = sm + 8448;     // 3*16*132
    float* qh   = sm + 14784;    // 64*20
    float* kh   = sm + 16064;    // 64*20
    float* vhT  = sm + 17344;    // 16*68
    float* s2   = sm + 18432;    // 64*68
    float* rsum = sm + 22784;    // 64

    const float* fb = feat + b * V * F;
    for (int i = t; i < 8192; i += 512) xs[(i >> 7) * 132 + (i & 127)] = fb[i];
    for (int i = t; i < 2048; i += 512) {
        int r = i >> 7, c = i & 127;
        wsl[0 * 2112 + r * 132 + c] = ldin(rwq, h * 2048 + i, fl);
        wsl[1 * 2112 + r * 132 + c] = ldin(rwk, h * 2048 + i, fl);
        wsl[2 * 2112 + r * 132 + c] = ldin(rwv, h * 2048 + i, fl);
    }
    __syncthreads();

    if (t < 256) {          // Q: 1v x 4d
        int v = t >> 2, d0 = (t & 3) * 4;
        float aq[4] = {};
        for (int kk = 0; kk < 128; kk += 4) {
            f4 X = *(const f4*)&xs[v * 132 + kk];
            #pragma unroll
            for (int i2 = 0; i2 < 4; i2++)
                aq[i2] += dot4(X, *(const f4*)&wsl[(d0 + i2) * 132 + kk]);
        }
        #pragma unroll
        for (int i2 = 0; i2 < 4; i2++) qh[v * 20 + d0 + i2] = aq[i2];
    } else if (t < 384) {   // K: 1v x 8d
        int tt = t - 256, v = tt >> 1, d0 = (tt & 1) * 8;
        float ak[8] = {};
        for (int kk = 0; kk < 128; kk += 4) {
            f4 X = *(const f4*)&xs[v * 132 + kk];
            #pragma unroll
            for (int i2 = 0; i2 < 8; i2++)
                ak[i2] += dot4(X, *(const f4*)&wsl[2112 + (d0 + i2) * 132 + kk]);
        }
        #pragma unroll
        for (int i2 = 0; i2 < 8; i2++) kh[v * 20 + d0 + i2] = ak[i2];
    } else {                // V -> transposed
        int tt = t - 384, v = tt >> 1, d0 = (tt & 1) * 8;
        float av[8] = {};
        for (int kk = 0; kk < 128; kk += 4) {
            f4 X = *(const f4*)&xs[v * 132 + kk];
            #pragma unroll
            for (int i2 = 0; i2 < 8; i2++)
                av[i2] += dot4(X, *(const f4*)&wsl[4224 + (d0 + i2) * 132 + kk]);
        }
        #pragma unroll
        for (int i2 = 0; i2 < 8; i2++) vhT[(d0 + i2) * 68 + v] = av[i2];
    }
    __syncthreads();

    {   // scores 64x64: all 512 thr, 4x2 tiles
        int v0 = t >> 5, l0 = t & 31;
        float sc[4][2] = {};
        #pragma unroll
        for (int kd = 0; kd < 16; kd += 4) {
            f4 Q[4], K2[2];
            #pragma unroll
            for (int m = 0; m < 4; m++) Q[m] = *(const f4*)&qh[(v0 + 16 * m) * 20 + kd];
            #pragma unroll
            for (int i2 = 0; i2 < 2; i2++) K2[i2] = *(const f4*)&kh[(l0 + 32 * i2) * 20 + kd];
            #pragma unroll
            for (int m = 0; m < 4; m++)
                #pragma unroll
                for (int i2 = 0; i2 < 2; i2++) sc[m][i2] += dot4(Q[m], K2[i2]);
        }
        #pragma unroll
        for (int m = 0; m < 4; m++)
            #pragma unroll
            for (int i2 = 0; i2 < 2; i2++)
                s2[(v0 + 16 * m) * 68 + l0 + 32 * i2] = sc[m][i2] * 0.25f;
    }
    __syncthreads();

    {   // softmax over 64
        int v = t >> 3, j = t & 7;
        float* sr = s2 + v * 68;
        float m = -1e30f;
        for (int k = j; k < V; k += 8) m = fmaxf(m, sr[k]);
        for (int off = 1; off < 8; off <<= 1) m = fmaxf(m, __shfl_xor(m, off));
        float sum = 0.f;
        for (int k = j; k < V; k += 8) { float e = __expf(sr[k] - m); sr[k] = e; sum += e; }
        for (int off = 1; off < 8; off <<= 1) sum += __shfl_xor(sum, off);
        if (j == 0) rsum[v] = sum;
    }
    __syncthreads();

    if (t < 256) {          // PV
        int v = t >> 2, d0 = (t & 3) * 4;
        float o4[4] = {};
        for (int ll = 0; ll < V; ll += 4) {
            f4 S4 = *(const f4*)&s2[v * 68 + ll];
            #pragma unroll
            for (int i2 = 0; i2 < 4; i2++)
                o4[i2] += dot4(S4, *(const f4*)&vhT[(d0 + i2) * 68 + ll]);
        }
        float* ob = osa + b * V * F + h * 16;
        float inv = 1.0f / rsum[v];
        #pragma unroll
        for (int i2 = 0; i2 < 4; i2++) ob[v * F + d0 + i2] = o4[i2] * inv;
    }
}

// ---------------- projres: feat = osa @ wcT + res, 8 bv per block ----------------
__device__ void phase_projres(float* sm, const float* ws, const float* osa,
                              const void* rinp, int wc_off, int mode,
                              float* feat, int bid, int fl) {
    int t = threadIdx.x;
    int bvl = t >> 6, tt = t & 63;
    int bv = bid * 8 + bvl;
    float* orow = sm + bvl * 128;
    orow[tt] = osa[bv * 128 + tt];
    orow[tt + 64] = osa[bv * 128 + tt + 64];
    __syncthreads();
    const float* wcT = ws + wc_off;
    float a0 = 0.f, a1 = 0.f;
    for (int k = 0; k < 128; k++) {
        float x = orow[k];
        a0 += x * wcT[k * 128 + tt];
        a1 += x * wcT[k * 128 + tt + 64];
    }
    float r0, r1;
    if (mode == 0) {
        int b = bv >> 6, v = bv & 63;
        float i00 = ldin(rinp, ((b * 2 + 0) * 64 + v) * 20 + 18, fl);
        float i01 = ldin(rinp, ((b * 2 + 0) * 64 + v) * 20 + 19, fl);
        float i10 = ldin(rinp, ((b * 2 + 1) * 64 + v) * 20 + 18, fl);
        float i11 = ldin(rinp, ((b * 2 + 1) * 64 + v) * 20 + 19, fl);
        const float* ew = ws + OFF_EMBW;
        r0 = ws[OFF_EMBB + tt] + i00 * ew[tt * 6 + 0] + i01 * ew[tt * 6 + 1]
           + i10 * ew[tt * 6 + 3] + i11 * ew[tt * 6 + 4];
        int u2 = tt + 64;
        r1 = ws[OFF_EMBB + u2] + i00 * ew[u2 * 6 + 0] + i01 * ew[u2 * 6 + 1]
           + i10 * ew[u2 * 6 + 3] + i11 * ew[u2 * 6 + 4];
    } else {
        r0 = feat[bv * 128 + tt];
        r1 = feat[bv * 128 + tt + 64];
    }
    feat[bv * 128 + tt] = a0 + r0;
    feat[bv * 128 + tt + 64] = a1 + r1;
}

// ---------------- output head + activation + direct broadcast write ----------------
__device__ void phase_out(float* sm, const float* ws, const float* ola,
                          const float* feat, const void* rpos, void* out,
                          int bid, int fl) {
    int t = threadIdx.x;
    int bvl = t >> 6, tt = t & 63;
    int bv = bid * 8 + bvl;
    float* orow = sm + bvl * 128;
    float* h3   = sm + 1024 + bvl * 128;
    float* z1   = sm + 2048 + bvl * 128;
    float* z2   = sm + 3072 + bvl * 128;
    float* z3all = sm + 4096;               // [8][40]
    float* z3   = z3all + bvl * 40;
    orow[tt] = ola[bv * 128 + tt];
    orow[tt + 64] = ola[bv * 128 + tt + 64];
    __syncthreads();
    const float* wclaT = ws + WCLA_T;
    float a0 = 0.f, a1 = 0.f;
    for (int k = 0; k < 128; k++) {
        float x = orow[k];
        a0 += x * wclaT[k * 128 + tt]; a1 += x * wclaT[k * 128 + tt + 64];
    }
    h3[tt] = a0 + feat[bv * 128 + tt];
    h3[tt + 64] = a1 + feat[bv * 128 + tt + 64];
    __syncthreads();
    const float* w1T = ws + W1_T;
    a0 = ws[OFF_B1 + tt]; a1 = ws[OFF_B1 + tt + 64];
    for (int k = 0; k < 128; k++) {
        float x = h3[k];
        a0 += x * w1T[k * 128 + tt]; a1 += x * w1T[k * 128 + tt + 64];
    }
    z1[tt] = fmaxf(a0, 0.f); z1[tt + 64] = fmaxf(a1, 0.f);
    __syncthreads();
    const float* w2T = ws + W2_T;
    a0 = ws[OFF_B2 + tt]; a1 = ws[OFF_B2 + tt + 64];
    for (int k = 0; k < 128; k++) {
        float x = z1[k];
        a0 += x * w2T[k * 128 + tt]; a1 += x * w2T[k * 128 + tt + 64];
    }
    z2[tt] = fmaxf(a0, 0.f); z2[tt + 64] = fmaxf(a1, 0.f);
    __syncthreads();
    const float* woT = ws + WO_T;
    if (tt < 36) {
        float a = ws[OFF_BO + tt];
        for (int k = 0; k < 128; k++) a += z2[k] * woT[k * 36 + tt];
        z3[tt] = a;
    }
    __syncthreads();
    float r = 0.f;
    if (tt < 36) {
        int c = tt % 6;
        float xv = z3[tt];
        if (c == 0)      r = xv + ldin(rpos, bv * 2 + 0, fl);
        else if (c == 1) r = xv + ldin(rpos, bv * 2 + 1, fl);
        else if (c == 2 || c == 3) r = __expf(0.5f * xv);
        else if (c == 4) r = tanhf(xv);
        else {
            const float inv = 0.4082482904638631f;  // 1/sqrt(6)
            float m = -1e30f;
            for (int pp = 0; pp < 6; pp++) m = fmaxf(m, z3[pp * 6 + 5] * inv);
            float sum = 0.f;
            for (int pp = 0; pp < 6; pp++) sum += __expf(z3[pp * 6 + 5] * inv - m);
            r = __expf(xv * inv - m) / sum;
        }
    }
    __syncthreads();
    if (tt < 36) z3[tt] = r;
    __syncthreads();
    // block writes 8 bv x 36 = 288 contiguous elements per timestep
    int base = bid * 288;
    if (fl) {
        float* o = (float*)out;
        for (int i = t; i < LEN_PRED * 288; i += 512) {
            int ttp = i / 288, idx = i - ttp * 288;
            o[ttp * 73728 + base + idx] = z3all[(idx / 36) * 40 + idx % 36];
        }
    } else {
        bf16* o = (bf16*)out;
        for (int i = t; i < LEN_PRED * 288; i += 512) {
            int ttp = i / 288, idx = i - ttp * 288;
            o[ttp * 73728 + base + idx] = __float2bfloat16(z3all[(idx / 36) * 40 + idx % 36]);
        }
    }
}

// ---------------- fused persistent kernel: 256 blocks x 512 thr ----------------
__global__ __launch_bounds__(512) void k_fused(InPtrs ptrs, float* __restrict__ ws,
                                               void* __restrict__ out) {
    int bid = blockIdx.x;
    int b = bid >> 3, h = bid & 7;
    int fl = detect_f32(ptrs.p[1], threadIdx.x);
    int* bar = (int*)(ws + OFF_BAR);
    float* feat = ws + OFF_FEAT;
    float* osa  = ws + OFF_OSA;
    __shared__ __align__(16) float sm[27712];   // ~110.8 KB -> 1 block/CU

    // P1: LaneAttentionPast (+ weight prep on blocks 0..10; P1 doesn't use ws weights)
    phase_attn_lane(sm, ptrs.p[5], ptrs.p[6], ptrs.p[7], ptrs.p[1], ptrs.p[0],
                    ptrs.p[3], ptrs.p[4], nullptr, 1, b, h, fl, osa);
    __syncthreads();
    if (bid < 11) phase_prep(sm, ptrs, fl, ws, bid);
    grid_bar(bar);
    // P2: feat = emb + osa @ wcP^T
    phase_projres(sm, ws, osa, ptrs.p[0], WCP_T, 0, feat, bid, fl);
    grid_bar(bar);
    // P3: SelfAttentionFut
    phase_saf(sm, ptrs.p[10], ptrs.p[9], ptrs.p[11], feat, b, h, fl, osa);
    grid_bar(bar);
    // P4: feat += osa @ wcSA^T
    phase_projres(sm, ws, osa, ptrs.p[0], WCSA_T, 1, feat, bid, fl);
    grid_bar(bar);
    // P5: LaneAttentionFut
    phase_attn_lane(sm, ptrs.p[15], ptrs.p[13], ptrs.p[14], ptrs.p[1], ptrs.p[0],
                    ptrs.p[3], ptrs.p[4], feat, 0, b, h, fl, osa);
    grid_bar(bar);
    // P6: output head + activation + broadcast write
    phase_out(sm, ws, osa, feat, ptrs.p[2], out, bid, fl);
}

extern "C" void kernel_launch(void* const* d_in, const int* in_sizes, int n_in,
                              void* d_out, int out_size, void* d_ws, size_t ws_size,
                              hipStream_t stream) {
    float* ws = (float*)d_ws;
    // zero the barrier state (ws is poisoned 0xAA); capture-legal async memset
    hipMemsetAsync((char*)d_ws + (size_t)OFF_BAR * 4, 0, 8, stream);
    InPtrs ptrs;
    for (int i = 0; i < 23; i++) ptrs.p[i] = d_in[i];
    k_fused<<<256, 512, 0, stream>>>(ptrs, ws, d_out);
}

// Round 7
// 200.704 us; speedup vs baseline: 1.4450x; 1.4450x over previous
//
#include <hip/hip_runtime.h>
#include <hip/hip_bf16.h>
#include <math.h>

typedef __hip_bfloat16 bf16;
typedef float4 f4;

#define B 32
#define V 64
#define F 128
#define NL 128
#define H 8
#define DH 16
#define LEN_PRED 30

// ---- f32 workspace layout (element offsets) ----
#define OFF_EMBW 0
#define OFF_EMBB 768
#define OFF_B1   896
#define OFF_B2   1024
#define OFF_BO   1152
#define WCP_T    1216
#define WCSA_T   17600
#define WCLA_T   33984
#define W1_T     50368
#define W2_T     66752
#define WO_T     83136
#define OFF_FEAT 87744
#define OFF_OSA  349888
#define OFF_BAR  612032      // 2 ints: {count, generation}

struct InPtrs { const void* p[23]; };

__device__ __forceinline__ float dot4(f4 a, f4 b) {
    return a.x * b.x + a.y * b.y + a.z * b.z + a.w * b.w;
}

// dtype detect: f32 read as u16 pairs has wild exponents in mantissa halves;
// bf16 N(0,1) never does. Uniform across all waves.
__device__ __forceinline__ int detect_f32(const void* lanesraw, int t) {
    const unsigned short* u = (const unsigned short*)lanesraw;
    int lane = t & 63;
    int wild = 0;
    for (int j = 0; j < 4; j++) {
        int e = (u[lane * 4 + j] >> 7) & 0xFF;
        if (e != 0 && (e < 90 || e > 164)) wild++;
    }
    unsigned long long m = __ballot(wild > 0);
    return (__popcll(m) >= 16) ? 1 : 0;
}

__device__ __forceinline__ float ldin(const void* p, int i, int fl) {
    return fl ? ((const float*)p)[i] : __bfloat162float(((const bf16*)p)[i]);
}

// grid-wide barrier: all 256 blocks co-resident (1 block/CU by LDS).
// RELAXED polling (agent-scope atomic loads read the coherent point without
// per-iteration cache invalidates); ordering established once: producers
// release via ACQ_REL fetch_add on count, winner RELEASEs the generation
// bump, spinners do a single ACQUIRE load after the spin exits.
__device__ __forceinline__ void grid_bar(int* bar) {
    __syncthreads();
    if (threadIdx.x == 0) {
        int g = __hip_atomic_load(bar + 1, __ATOMIC_RELAXED, __HIP_MEMORY_SCOPE_AGENT);
        int v = __hip_atomic_fetch_add(bar, 1, __ATOMIC_ACQ_REL, __HIP_MEMORY_SCOPE_AGENT);
        if (v == (int)gridDim.x - 1) {
            __hip_atomic_store(bar, 0, __ATOMIC_RELAXED, __HIP_MEMORY_SCOPE_AGENT);
            __hip_atomic_fetch_add(bar + 1, 1, __ATOMIC_RELEASE, __HIP_MEMORY_SCOPE_AGENT);
        } else {
            while (__hip_atomic_load(bar + 1, __ATOMIC_RELAXED, __HIP_MEMORY_SCOPE_AGENT) == g)
                __builtin_amdgcn_s_sleep(8);
            (void)__hip_atomic_load(bar + 1, __ATOMIC_ACQUIRE, __HIP_MEMORY_SCOPE_AGENT);
        }
    }
    __syncthreads();
}

// ---------------- prep: vec copies + 6 weight transposes (blocks 0..10) ----------------
__device__ void phase_prep(float* sm, const InPtrs& ptrs, int fl, float* ws, int seg) {
    const int srci[11] = {3, 4, 18, 20, 22, 8, 12, 16, 17, 19, 21};
    const int szs[11]  = {768, 128, 128, 128, 36, 16384, 16384, 16384, 16384, 16384, 4608};
    const int dsto[11] = {OFF_EMBW, OFF_EMBB, OFF_B1, OFF_B2, OFF_BO,
                          WCP_T, WCSA_T, WCLA_T, W1_T, W2_T, WO_T};
    const int Otab[11] = {0, 0, 0, 0, 0, 128, 128, 128, 128, 128, 36};
    int t = threadIdx.x;
    int n = szs[seg], O = Otab[seg];
    const void* src = ptrs.p[srci[seg]];
    if (O == 0) {
        for (int i = t; i < n; i += 512) ws[dsto[seg] + i] = ldin(src, i, fl);
        return;
    }
    float* tile = sm;                       // 128*129 = 16512 floats
    for (int i = t; i < n; i += 512) {
        int o = i >> 7, k = i & 127;
        tile[o * 129 + k] = ldin(src, i, fl);
    }
    __syncthreads();
    float* dst = ws + dsto[seg];
    for (int j = t; j < n; j += 512) {
        int k = j / O, o = j - k * O;
        dst[j] = tile[o * 129 + k];
    }
}

// ---------------- lane attention (past & fut), per (b,h) ----------------
__device__ void phase_attn_lane(float* sm, const void* rwq, const void* rwk,
        const void* rwv, const void* rlanes, const void* rinp,
        const void* rembw, const void* rembb, const float* xsrc, int use_emb,
        int b, int h, int fl, float* osa) {
    int t = threadIdx.x;
    float* ln   = sm;            // 128*68 (aliased by scores later)
    float* xs   = sm + 8704;     // 64*132
    float* wql  = sm + 17152;    // 16*132
    float* wkl  = sm + 19264;    // 16*68
    float* wvl  = sm + 20352;    // 16*68
    float* kh   = sm + 21440;    // 128*20
    float* vhT  = sm + 24000;    // 16*132
    float* qh   = sm + 26112;    // 64*20
    float* rsum = sm + 27392;    // 64
    float* in4  = sm + 27456;    // 256
    float* s    = ln;

    int lb = b * NL * 64;
    for (int i = t; i < NL * 64; i += 512)
        ln[(i >> 6) * 68 + (i & 63)] = ldin(rlanes, lb + i, fl);
    for (int i = t; i < 16 * 128; i += 512)
        wql[(i >> 7) * 132 + (i & 127)] = ldin(rwq, h * 2048 + i, fl);
    for (int i = t; i < 16 * 64; i += 512)
        wkl[(i >> 6) * 68 + (i & 63)] = ldin(rwk, h * 1024 + i, fl);
    for (int i = t; i < 16 * 64; i += 512)
        wvl[(i >> 6) * 68 + (i & 63)] = ldin(rwv, h * 1024 + i, fl);
    if (use_emb) {
        if (t < 64) {
            in4[t * 4 + 0] = ldin(rinp, ((b * 2 + 0) * 64 + t) * 20 + 18, fl);
            in4[t * 4 + 1] = ldin(rinp, ((b * 2 + 0) * 64 + t) * 20 + 19, fl);
            in4[t * 4 + 2] = ldin(rinp, ((b * 2 + 1) * 64 + t) * 20 + 18, fl);
            in4[t * 4 + 3] = ldin(rinp, ((b * 2 + 1) * 64 + t) * 20 + 19, fl);
        }
        __syncthreads();
        for (int i = t; i < 8192; i += 512) {
            int v = i >> 7, c = i & 127;
            xs[v * 132 + c] = ldin(rembb, c, fl)
                + in4[v * 4 + 0] * ldin(rembw, c * 6 + 0, fl)
                + in4[v * 4 + 1] * ldin(rembw, c * 6 + 1, fl)
                + in4[v * 4 + 2] * ldin(rembw, c * 6 + 3, fl)
                + in4[v * 4 + 3] * ldin(rembw, c * 6 + 4, fl);
        }
    } else {
        const float* fb = xsrc + b * V * F;
        for (int i = t; i < 8192; i += 512) xs[(i >> 7) * 132 + (i & 127)] = fb[i];
    }
    __syncthreads();

    // proj: t<256 -> K,V (8 out each per mat); t>=256 -> Q (4 out)
    if (t < 256) {
        int l0 = t >> 3, d0 = (t & 7) * 2;
        float ak[4][2] = {}, av[4][2] = {};
        for (int kk = 0; kk < 64; kk += 4) {
            f4 L[4], WK[2], WV[2];
            #pragma unroll
            for (int m = 0; m < 4; m++) L[m] = *(const f4*)&ln[(l0 + 32 * m) * 68 + kk];
            #pragma unroll
            for (int j = 0; j < 2; j++) {
                WK[j] = *(const f4*)&wkl[(d0 + j) * 68 + kk];
                WV[j] = *(const f4*)&wvl[(d0 + j) * 68 + kk];
            }
            #pragma unroll
            for (int m = 0; m < 4; m++)
                #pragma unroll
                for (int j = 0; j < 2; j++) {
                    ak[m][j] += dot4(L[m], WK[j]);
                    av[m][j] += dot4(L[m], WV[j]);
                }
        }
        #pragma unroll
        for (int m = 0; m < 4; m++)
            #pragma unroll
            for (int j = 0; j < 2; j++) {
                int l = l0 + 32 * m, d = d0 + j;
                kh[l * 20 + d] = ak[m][j];
                vhT[d * 132 + l] = av[m][j];
            }
    } else {
        int tt = t - 256, v = tt >> 2, d0 = (tt & 3) * 4;
        float aq[4] = {};
        for (int kk = 0; kk < 128; kk += 4) {
            f4 X = *(const f4*)&xs[v * 132 + kk];
            #pragma unroll
            for (int i2 = 0; i2 < 4; i2++)
                aq[i2] += dot4(X, *(const f4*)&wql[(d0 + i2) * 132 + kk]);
        }
        #pragma unroll
        for (int i2 = 0; i2 < 4; i2++) qh[v * 20 + d0 + i2] = aq[i2];
    }
    __syncthreads();

    // scores: all 512 thr, 4x4 tiles; writes into s (= dead ln region)
    {
        int v0 = t >> 5, l0 = t & 31;
        float sc[4][4] = {};
        #pragma unroll
        for (int kd = 0; kd < 16; kd += 4) {
            f4 Q[4], K4[4];
            #pragma unroll
            for (int m = 0; m < 4; m++) Q[m] = *(const f4*)&qh[(v0 + 16 * m) * 20 + kd];
            #pragma unroll
            for (int i2 = 0; i2 < 4; i2++) K4[i2] = *(const f4*)&kh[(l0 + 32 * i2) * 20 + kd];
            #pragma unroll
            for (int m = 0; m < 4; m++)
                #pragma unroll
                for (int i2 = 0; i2 < 4; i2++) sc[m][i2] += dot4(Q[m], K4[i2]);
        }
        #pragma unroll
        for (int m = 0; m < 4; m++)
            #pragma unroll
            for (int i2 = 0; i2 < 4; i2++)
                s[(v0 + 16 * m) * 132 + l0 + 32 * i2] = sc[m][i2] * 0.25f;
    }
    __syncthreads();

    {   // softmax: 8 lanes per row
        int v = t >> 3, j = t & 7;
        float* sr = s + v * 132;
        float m = -1e30f;
        for (int k = j; k < NL; k += 8) m = fmaxf(m, sr[k]);
        for (int off = 1; off < 8; off <<= 1) m = fmaxf(m, __shfl_xor(m, off));
        float sum = 0.f;
        for (int k = j; k < NL; k += 8) { float e = __expf(sr[k] - m); sr[k] = e; sum += e; }
        for (int off = 1; off < 8; off <<= 1) sum += __shfl_xor(sum, off);
        if (j == 0) rsum[v] = sum;
    }
    __syncthreads();

    // PV: 256 thr, 1v x 4d
    if (t < 256) {
        int v = t >> 2, d0 = (t & 3) * 4;
        float o4[4] = {};
        for (int ll = 0; ll < NL; ll += 4) {
            f4 S4 = *(const f4*)&s[v * 132 + ll];
            #pragma unroll
            for (int i2 = 0; i2 < 4; i2++)
                o4[i2] += dot4(S4, *(const f4*)&vhT[(d0 + i2) * 132 + ll]);
        }
        float* ob = osa + b * V * F + h * 16;
        float inv = 1.0f / rsum[v];
        #pragma unroll
        for (int i2 = 0; i2 < 4; i2++) ob[v * F + d0 + i2] = o4[i2] * inv;
    }
}

// ---------------- SelfAttentionFut, per (b,h) ----------------
__device__ void phase_saf(float* sm, const void* rwq, const void* rwk, const void* rwv,
                          const float* feat, int b, int h, int fl, float* osa) {
    int t = threadIdx.x;
    float* xs   = sm;            // 64*132
    float* wsl  = sm + 8448;     // 3*16*132
    float* qh   = sm + 14784;    // 64*20
    float* kh   = sm + 16064;    // 64*20
    float* vhT  = sm + 17344;    // 16*68
    float* s2   = sm + 18432;    // 64*68
    float* rsum = sm + 22784;    // 64

    const float* fb = feat + b * V * F;
    for (int i = t; i < 8192; i += 512) xs[(i >> 7) * 132 + (i & 127)] = fb[i];
    for (int i = t; i < 2048; i += 512) {
        int r = i >> 7, c = i & 127;
        wsl[0 * 2112 + r * 132 + c] = ldin(rwq, h * 2048 + i, fl);
        wsl[1 * 2112 + r * 132 + c] = ldin(rwk, h * 2048 + i, fl);
        wsl[2 * 2112 + r * 132 + c] = ldin(rwv, h * 2048 + i, fl);
    }
    __syncthreads();

    if (t < 256) {          // Q: 1v x 4d
        int v = t >> 2, d0 = (t & 3) * 4;
        float aq[4] = {};
        for (int kk = 0; kk < 128; kk += 4) {
            f4 X = *(const f4*)&xs[v * 132 + kk];
            #pragma unroll
            for (int i2 = 0; i2 < 4; i2++)
                aq[i2] += dot4(X, *(const f4*)&wsl[(d0 + i2) * 132 + kk]);
        }
        #pragma unroll
        for (int i2 = 0; i2 < 4; i2++) qh[v * 20 + d0 + i2] = aq[i2];
    } else if (t < 384) {   // K: 1v x 8d
        int tt = t - 256, v = tt >> 1, d0 = (tt & 1) * 8;
        float ak[8] = {};
        for (int kk = 0; kk < 128; kk += 4) {
            f4 X = *(const f4*)&xs[v * 132 + kk];
            #pragma unroll
            for (int i2 = 0; i2 < 8; i2++)
                ak[i2] += dot4(X, *(const f4*)&wsl[2112 + (d0 + i2) * 132 + kk]);
        }
        #pragma unroll
        for (int i2 = 0; i2 < 8; i2++) kh[v * 20 + d0 + i2] = ak[i2];
    } else {                // V -> transposed
        int tt = t - 384, v = tt >> 1, d0 = (tt & 1) * 8;
        float av[8] = {};
        for (int kk = 0; kk < 128; kk += 4) {
            f4 X = *(const f4*)&xs[v * 132 + kk];
            #pragma unroll
            for (int i2 = 0; i2 < 8; i2++)
                av[i2] += dot4(X, *(const f4*)&wsl[4224 + (d0 + i2) * 132 + kk]);
        }
        #pragma unroll
        for (int i2 = 0; i2 < 8; i2++) vhT[(d0 + i2) * 68 + v] = av[i2];
    }
    __syncthreads();

    {   // scores 64x64: all 512 thr, 4x2 tiles
        int v0 = t >> 5, l0 = t & 31;
        float sc[4][2] = {};
        #pragma unroll
        for (int kd = 0; kd < 16; kd += 4) {
            f4 Q[4], K2[2];
            #pragma unroll
            for (int m = 0; m < 4; m++) Q[m] = *(const f4*)&qh[(v0 + 16 * m) * 20 + kd];
            #pragma unroll
            for (int i2 = 0; i2 < 2; i2++) K2[i2] = *(const f4*)&kh[(l0 + 32 * i2) * 20 + kd];
            #pragma unroll
            for (int m = 0; m < 4; m++)
                #pragma unroll
                for (int i2 = 0; i2 < 2; i2++) sc[m][i2] += dot4(Q[m], K2[i2]);
        }
        #pragma unroll
        for (int m = 0; m < 4; m++)
            #pragma unroll
            for (int i2 = 0; i2 < 2; i2++)
                s2[(v0 + 16 * m) * 68 + l0 + 32 * i2] = sc[m][i2] * 0.25f;
    }
    __syncthreads();

    {   // softmax over 64
        int v = t >> 3, j = t & 7;
        float* sr = s2 + v * 68;
        float m = -1e30f;
        for (int k = j; k < V; k += 8) m = fmaxf(m, sr[k]);
        for (int off = 1; off < 8; off <<= 1) m = fmaxf(m, __shfl_xor(m, off));
        float sum = 0.f;
        for (int k = j; k < V; k += 8) { float e = __expf(sr[k] - m); sr[k] = e; sum += e; }
        for (int off = 1; off < 8; off <<= 1) sum += __shfl_xor(sum, off);
        if (j == 0) rsum[v] = sum;
    }
    __syncthreads();

    if (t < 256) {          // PV
        int v = t >> 2, d0 = (t & 3) * 4;
        float o4[4] = {};
        for (int ll = 0; ll < V; ll += 4) {
            f4 S4 = *(const f4*)&s2[v * 68 + ll];
            #pragma unroll
            for (int i2 = 0; i2 < 4; i2++)
                o4[i2] += dot4(S4, *(const f4*)&vhT[(d0 + i2) * 68 + ll]);
        }
        float* ob = osa + b * V * F + h * 16;
        float inv = 1.0f / rsum[v];
        #pragma unroll
        for (int i2 = 0; i2 < 4; i2++) ob[v * F + d0 + i2] = o4[i2] * inv;
    }
}

// ---------------- projres: feat = osa @ wcT + res, 8 bv per block ----------------
__device__ void phase_projres(float* sm, const float* ws, const float* osa,
                              const void* rinp, int wc_off, int mode,
                              float* feat, int bid, int fl) {
    int t = threadIdx.x;
    int bvl = t >> 6, tt = t & 63;
    int bv = bid * 8 + bvl;
    float* orow = sm + bvl * 128;
    orow[tt] = osa[bv * 128 + tt];
    orow[tt + 64] = osa[bv * 128 + tt + 64];
    __syncthreads();
    const float* wcT = ws + wc_off;
    float a0 = 0.f, a1 = 0.f;
    for (int k = 0; k < 128; k++) {
        float x = orow[k];
        a0 += x * wcT[k * 128 + tt];
        a1 += x * wcT[k * 128 + tt + 64];
    }
    float r0, r1;
    if (mode == 0) {
        int b = bv >> 6, v = bv & 63;
        float i00 = ldin(rinp, ((b * 2 + 0) * 64 + v) * 20 + 18, fl);
        float i01 = ldin(rinp, ((b * 2 + 0) * 64 + v) * 20 + 19, fl);
        float i10 = ldin(rinp, ((b * 2 + 1) * 64 + v) * 20 + 18, fl);
        float i11 = ldin(rinp, ((b * 2 + 1) * 64 + v) * 20 + 19, fl);
        const float* ew = ws + OFF_EMBW;
        r0 = ws[OFF_EMBB + tt] + i00 * ew[tt * 6 + 0] + i01 * ew[tt * 6 + 1]
           + i10 * ew[tt * 6 + 3] + i11 * ew[tt * 6 + 4];
        int u2 = tt + 64;
        r1 = ws[OFF_EMBB + u2] + i00 * ew[u2 * 6 + 0] + i01 * ew[u2 * 6 + 1]
           + i10 * ew[u2 * 6 + 3] + i11 * ew[u2 * 6 + 4];
    } else {
        r0 = feat[bv * 128 + tt];
        r1 = feat[bv * 128 + tt + 64];
    }
    feat[bv * 128 + tt] = a0 + r0;
    feat[bv * 128 + tt + 64] = a1 + r1;
}

// ---------------- output head + activation + direct broadcast write ----------------
__device__ void phase_out(float* sm, const float* ws, const float* ola,
                          const float* feat, const void* rpos, void* out,
                          int bid, int fl) {
    int t = threadIdx.x;
    int bvl = t >> 6, tt = t & 63;
    int bv = bid * 8 + bvl;
    float* orow = sm + bvl * 128;
    float* h3   = sm + 1024 + bvl * 128;
    float* z1   = sm + 2048 + bvl * 128;
    float* z2   = sm + 3072 + bvl * 128;
    float* z3all = sm + 4096;               // [8][40]
    float* z3   = z3all + bvl * 40;
    orow[tt] = ola[bv * 128 + tt];
    orow[tt + 64] = ola[bv * 128 + tt + 64];
    __syncthreads();
    const float* wclaT = ws + WCLA_T;
    float a0 = 0.f, a1 = 0.f;
    for (int k = 0; k < 128; k++) {
        float x = orow[k];
        a0 += x * wclaT[k * 128 + tt]; a1 += x * wclaT[k * 128 + tt + 64];
    }
    h3[tt] = a0 + feat[bv * 128 + tt];
    h3[tt + 64] = a1 + feat[bv * 128 + tt + 64];
    __syncthreads();
    const float* w1T = ws + W1_T;
    a0 = ws[OFF_B1 + tt]; a1 = ws[OFF_B1 + tt + 64];
    for (int k = 0; k < 128; k++) {
        float x = h3[k];
        a0 += x * w1T[k * 128 + tt]; a1 += x * w1T[k * 128 + tt + 64];
    }
    z1[tt] = fmaxf(a0, 0.f); z1[tt + 64] = fmaxf(a1, 0.f);
    __syncthreads();
    const float* w2T = ws + W2_T;
    a0 = ws[OFF_B2 + tt]; a1 = ws[OFF_B2 + tt + 64];
    for (int k = 0; k < 128; k++) {
        float x = z1[k];
        a0 += x * w2T[k * 128 + tt]; a1 += x * w2T[k * 128 + tt + 64];
    }
    z2[tt] = fmaxf(a0, 0.f); z2[tt + 64] = fmaxf(a1, 0.f);
    __syncthreads();
    const float* woT = ws + WO_T;
    if (tt < 36) {
        float a = ws[OFF_BO + tt];
        for (int k = 0; k < 128; k++) a += z2[k] * woT[k * 36 + tt];
        z3[tt] = a;
    }
    __syncthreads();
    float r = 0.f;
    if (tt < 36) {
        int c = tt % 6;
        float xv = z3[tt];
        if (c == 0)      r = xv + ldin(rpos, bv * 2 + 0, fl);
        else if (c == 1) r = xv + ldin(rpos, bv * 2 + 1, fl);
        else if (c == 2 || c == 3) r = __expf(0.5f * xv);
        else if (c == 4) r = tanhf(xv);
        else {
            const float inv = 0.4082482904638631f;  // 1/sqrt(6)
            float m = -1e30f;
            for (int pp = 0; pp < 6; pp++) m = fmaxf(m, z3[pp * 6 + 5] * inv);
            float sum = 0.f;
            for (int pp = 0; pp < 6; pp++) sum += __expf(z3[pp * 6 + 5] * inv - m);
            r = __expf(xv * inv - m) / sum;
        }
    }
    __syncthreads();
    if (tt < 36) z3[tt] = r;
    __syncthreads();
    // block writes 8 bv x 36 = 288 contiguous elements per timestep
    int base = bid * 288;
    if (fl) {
        float* o = (float*)out;
        for (int i = t; i < LEN_PRED * 288; i += 512) {
            int ttp = i / 288, idx = i - ttp * 288;
            o[ttp * 73728 + base + idx] = z3all[(idx / 36) * 40 + idx % 36];
        }
    } else {
        bf16* o = (bf16*)out;
        for (int i = t; i < LEN_PRED * 288; i += 512) {
            int ttp = i / 288, idx = i - ttp * 288;
            o[ttp * 73728 + base + idx] = __float2bfloat16(z3all[(idx / 36) * 40 + idx % 36]);
        }
    }
}

// ---------------- fused persistent kernel: 256 blocks x 512 thr ----------------
__global__ __launch_bounds__(512) void k_fused(InPtrs ptrs, float* __restrict__ ws,
                                               void* __restrict__ out) {
    int bid = blockIdx.x;
    int b = bid >> 3, h = bid & 7;
    int fl = detect_f32(ptrs.p[1], threadIdx.x);
    int* bar = (int*)(ws + OFF_BAR);
    float* feat = ws + OFF_FEAT;
    float* osa  = ws + OFF_OSA;
    __shared__ __align__(16) float sm[27712];   // ~110.8 KB -> 1 block/CU

    // P1: LaneAttentionPast (+ weight prep on blocks 0..10; P1 doesn't use ws weights)
    phase_attn_lane(sm, ptrs.p[5], ptrs.p[6], ptrs.p[7], ptrs.p[1], ptrs.p[0],
                    ptrs.p[3], ptrs.p[4], nullptr, 1, b, h, fl, osa);
    __syncthreads();
    if (bid < 11) phase_prep(sm, ptrs, fl, ws, bid);
    grid_bar(bar);
    // P2: feat = emb + osa @ wcP^T
    phase_projres(sm, ws, osa, ptrs.p[0], WCP_T, 0, feat, bid, fl);
    grid_bar(bar);
    // P3: SelfAttentionFut
    phase_saf(sm, ptrs.p[10], ptrs.p[9], ptrs.p[11], feat, b, h, fl, osa);
    grid_bar(bar);
    // P4: feat += osa @ wcSA^T
    phase_projres(sm, ws, osa, ptrs.p[0], WCSA_T, 1, feat, bid, fl);
    grid_bar(bar);
    // P5: LaneAttentionFut
    phase_attn_lane(sm, ptrs.p[15], ptrs.p[13], ptrs.p[14], ptrs.p[1], ptrs.p[0],
                    ptrs.p[3], ptrs.p[4], feat, 0, b, h, fl, osa);
    grid_bar(bar);
    // P6: output head + activation + broadcast write
    phase_out(sm, ws, osa, feat, ptrs.p[2], out, bid, fl);
}

extern "C" void kernel_launch(void* const* d_in, const int* in_sizes, int n_in,
                              void* d_out, int out_size, void* d_ws, size_t ws_size,
                              hipStream_t stream) {
    float* ws = (float*)d_ws;
    // zero the barrier state (ws is poisoned 0xAA); capture-legal async memset
    hipMemsetAsync((char*)d_ws + (size_t)OFF_BAR * 4, 0, 8, stream);
    InPtrs ptrs;
    for (int i = 0; i < 23; i++) ptrs.p[i] = d_in[i];
    k_fused<<<256, 512, 0, stream>>>(ptrs, ws, d_out);
}

// Round 8
// 158.047 us; speedup vs baseline: 1.8349x; 1.2699x over previous
//
#include <hip/hip_runtime.h>
#include <hip/hip_bf16.h>
#include <math.h>

typedef __hip_bfloat16 bf16;
typedef float4 f4;

#define B 32
#define V 64
#define F 128
#define NL 128
#define H 8
#define DH 16
#define LEN_PRED 30

// ---- f32 workspace layout (element offsets) ----
#define OFF_EMBW 0
#define OFF_EMBB 768
#define OFF_B1   896
#define OFF_B2   1024
#define OFF_BO   1152
#define WCP_T    1216
#define WCSA_T   17600
#define WCLA_T   33984
#define W1_T     50368
#define W2_T     66752
#define WO_T     83136
#define OFF_FEAT 87744
#define OFF_OSA  349888
#define OFF_BAR  612032      // flags[256*32] ints + gen int (memset at launch)

struct InPtrs { const void* p[23]; };

__device__ __forceinline__ float dot4(f4 a, f4 b) {
    return a.x * b.x + a.y * b.y + a.z * b.z + a.w * b.w;
}

// dtype detect: f32 read as u16 pairs has wild exponents in mantissa halves;
// bf16 N(0,1) never does. Uniform across all waves.
__device__ __forceinline__ int detect_f32(const void* lanesraw, int t) {
    const unsigned short* u = (const unsigned short*)lanesraw;
    int lane = t & 63;
    int wild = 0;
    for (int j = 0; j < 4; j++) {
        int e = (u[lane * 4 + j] >> 7) & 0xFF;
        if (e != 0 && (e < 90 || e > 164)) wild++;
    }
    unsigned long long m = __ballot(wild > 0);
    return (__popcll(m) >= 16) ? 1 : 0;
}

__device__ __forceinline__ float ldin(const void* p, int i, int fl) {
    return fl ? ((const float*)p)[i] : __bfloat162float(((const bf16*)p)[i]);
}

// grid-wide flag barrier: no contended RMW. Each block RELEASE-stores its own
// padded flag (own cacheline); block 0's wave 0 polls all flags relaxed, then
// RELEASE-stores the generation; spinners poll gen relaxed + one ACQUIRE load.
__device__ __forceinline__ void grid_bar(int* flags, int* gen, int bid, int phase) {
    __syncthreads();
    int t = threadIdx.x;
    if (bid == 0) {
        if (t < 64) {
            for (;;) {
                int mn = 0x7fffffff;
                for (int i = t; i < 256; i += 64) {
                    if (i == 0) continue;
                    int f = __hip_atomic_load(flags + i * 32, __ATOMIC_RELAXED,
                                              __HIP_MEMORY_SCOPE_AGENT);
                    mn = min(mn, f);
                }
                if (__all(mn >= phase)) break;
                __builtin_amdgcn_s_sleep(1);
            }
            if (t == 0) {
                (void)__hip_atomic_load(gen, __ATOMIC_ACQUIRE, __HIP_MEMORY_SCOPE_AGENT);
                __hip_atomic_store(gen, phase, __ATOMIC_RELEASE, __HIP_MEMORY_SCOPE_AGENT);
            }
        }
    } else if (t == 0) {
        __hip_atomic_store(flags + bid * 32, phase, __ATOMIC_RELEASE,
                           __HIP_MEMORY_SCOPE_AGENT);
        while (__hip_atomic_load(gen, __ATOMIC_RELAXED, __HIP_MEMORY_SCOPE_AGENT) < phase)
            __builtin_amdgcn_s_sleep(4);
        (void)__hip_atomic_load(gen, __ATOMIC_ACQUIRE, __HIP_MEMORY_SCOPE_AGENT);
    }
    __syncthreads();
}

// ---------------- prep: vec copies + 6 weight transposes (blocks 245..255) ----------------
__device__ void phase_prep(float* sm, const InPtrs& ptrs, int fl, float* ws, int seg) {
    const int srci[11] = {3, 4, 18, 20, 22, 8, 12, 16, 17, 19, 21};
    const int szs[11]  = {768, 128, 128, 128, 36, 16384, 16384, 16384, 16384, 16384, 4608};
    const int dsto[11] = {OFF_EMBW, OFF_EMBB, OFF_B1, OFF_B2, OFF_BO,
                          WCP_T, WCSA_T, WCLA_T, W1_T, W2_T, WO_T};
    const int Otab[11] = {0, 0, 0, 0, 0, 128, 128, 128, 128, 128, 36};
    int t = threadIdx.x;
    int n = szs[seg], O = Otab[seg];
    const void* src = ptrs.p[srci[seg]];
    if (O == 0) {
        for (int i = t; i < n; i += 512) ws[dsto[seg] + i] = ldin(src, i, fl);
        return;
    }
    float* tile = sm;                       // 128*129 = 16512 floats
    for (int i = t; i < n; i += 512) {
        int o = i >> 7, k = i & 127;
        tile[o * 129 + k] = ldin(src, i, fl);
    }
    __syncthreads();
    float* dst = ws + dsto[seg];
    for (int j = t; j < n; j += 512) {
        int k = j / O, o = j - k * O;
        dst[j] = tile[o * 129 + k];
    }
}

// ---------------- lane attention (past & fut), per (b,h) ----------------
__device__ void phase_attn_lane(float* sm, const void* rwq, const void* rwk,
        const void* rwv, const void* rlanes, const void* rinp,
        const void* rembw, const void* rembb, const float* xsrc, int use_emb,
        int b, int h, int fl, float* osa) {
    int t = threadIdx.x;
    float* ln   = sm;            // 128*68 (aliased by scores later)
    float* xs   = sm + 8704;     // 64*132
    float* wql  = sm + 17152;    // 16*132
    float* wkl  = sm + 19264;    // 16*68
    float* wvl  = sm + 20352;    // 16*68
    float* kh   = sm + 21440;    // 128*20
    float* vhT  = sm + 24000;    // 16*132
    float* qh   = sm + 26112;    // 64*20
    float* rsum = sm + 27392;    // 64
    float* in4  = sm + 27456;    // 256
    float* s    = ln;

    int lb = b * NL * 64;
    for (int i = t; i < NL * 64; i += 512)
        ln[(i >> 6) * 68 + (i & 63)] = ldin(rlanes, lb + i, fl);
    for (int i = t; i < 16 * 128; i += 512)
        wql[(i >> 7) * 132 + (i & 127)] = ldin(rwq, h * 2048 + i, fl);
    for (int i = t; i < 16 * 64; i += 512)
        wkl[(i >> 6) * 68 + (i & 63)] = ldin(rwk, h * 1024 + i, fl);
    for (int i = t; i < 16 * 64; i += 512)
        wvl[(i >> 6) * 68 + (i & 63)] = ldin(rwv, h * 1024 + i, fl);
    if (use_emb) {
        if (t < 64) {
            in4[t * 4 + 0] = ldin(rinp, ((b * 2 + 0) * 64 + t) * 20 + 18, fl);
            in4[t * 4 + 1] = ldin(rinp, ((b * 2 + 0) * 64 + t) * 20 + 19, fl);
            in4[t * 4 + 2] = ldin(rinp, ((b * 2 + 1) * 64 + t) * 20 + 18, fl);
            in4[t * 4 + 3] = ldin(rinp, ((b * 2 + 1) * 64 + t) * 20 + 19, fl);
        }
        __syncthreads();
        for (int i = t; i < 8192; i += 512) {
            int v = i >> 7, c = i & 127;
            xs[v * 132 + c] = ldin(rembb, c, fl)
                + in4[v * 4 + 0] * ldin(rembw, c * 6 + 0, fl)
                + in4[v * 4 + 1] * ldin(rembw, c * 6 + 1, fl)
                + in4[v * 4 + 2] * ldin(rembw, c * 6 + 3, fl)
                + in4[v * 4 + 3] * ldin(rembw, c * 6 + 4, fl);
        }
    } else {
        const float* fb = xsrc + b * V * F;
        for (int i = t; i < 8192; i += 512) xs[(i >> 7) * 132 + (i & 127)] = fb[i];
    }
    __syncthreads();

    // proj: t<256 -> K,V (8 out each per mat); t>=256 -> Q (4 out)
    if (t < 256) {
        int l0 = t >> 3, d0 = (t & 7) * 2;
        float ak[4][2] = {}, av[4][2] = {};
        for (int kk = 0; kk < 64; kk += 4) {
            f4 L[4], WK[2], WV[2];
            #pragma unroll
            for (int m = 0; m < 4; m++) L[m] = *(const f4*)&ln[(l0 + 32 * m) * 68 + kk];
            #pragma unroll
            for (int j = 0; j < 2; j++) {
                WK[j] = *(const f4*)&wkl[(d0 + j) * 68 + kk];
                WV[j] = *(const f4*)&wvl[(d0 + j) * 68 + kk];
            }
            #pragma unroll
            for (int m = 0; m < 4; m++)
                #pragma unroll
                for (int j = 0; j < 2; j++) {
                    ak[m][j] += dot4(L[m], WK[j]);
                    av[m][j] += dot4(L[m], WV[j]);
                }
        }
        #pragma unroll
        for (int m = 0; m < 4; m++)
            #pragma unroll
            for (int j = 0; j < 2; j++) {
                int l = l0 + 32 * m, d = d0 + j;
                kh[l * 20 + d] = ak[m][j];
                vhT[d * 132 + l] = av[m][j];
            }
    } else {
        int tt = t - 256, v = tt >> 2, d0 = (tt & 3) * 4;
        float aq[4] = {};
        for (int kk = 0; kk < 128; kk += 4) {
            f4 X = *(const f4*)&xs[v * 132 + kk];
            #pragma unroll
            for (int i2 = 0; i2 < 4; i2++)
                aq[i2] += dot4(X, *(const f4*)&wql[(d0 + i2) * 132 + kk]);
        }
        #pragma unroll
        for (int i2 = 0; i2 < 4; i2++) qh[v * 20 + d0 + i2] = aq[i2];
    }
    __syncthreads();

    // scores: all 512 thr, 4x4 tiles; writes into s (= dead ln region)
    {
        int v0 = t >> 5, l0 = t & 31;
        float sc[4][4] = {};
        #pragma unroll
        for (int kd = 0; kd < 16; kd += 4) {
            f4 Q[4], K4[4];
            #pragma unroll
            for (int m = 0; m < 4; m++) Q[m] = *(const f4*)&qh[(v0 + 16 * m) * 20 + kd];
            #pragma unroll
            for (int i2 = 0; i2 < 4; i2++) K4[i2] = *(const f4*)&kh[(l0 + 32 * i2) * 20 + kd];
            #pragma unroll
            for (int m = 0; m < 4; m++)
                #pragma unroll
                for (int i2 = 0; i2 < 4; i2++) sc[m][i2] += dot4(Q[m], K4[i2]);
        }
        #pragma unroll
        for (int m = 0; m < 4; m++)
            #pragma unroll
            for (int i2 = 0; i2 < 4; i2++)
                s[(v0 + 16 * m) * 132 + l0 + 32 * i2] = sc[m][i2] * 0.25f;
    }
    __syncthreads();

    {   // softmax: 8 lanes per row
        int v = t >> 3, j = t & 7;
        float* sr = s + v * 132;
        float m = -1e30f;
        for (int k = j; k < NL; k += 8) m = fmaxf(m, sr[k]);
        for (int off = 1; off < 8; off <<= 1) m = fmaxf(m, __shfl_xor(m, off));
        float sum = 0.f;
        for (int k = j; k < NL; k += 8) { float e = __expf(sr[k] - m); sr[k] = e; sum += e; }
        for (int off = 1; off < 8; off <<= 1) sum += __shfl_xor(sum, off);
        if (j == 0) rsum[v] = sum;
    }
    __syncthreads();

    // PV: 256 thr, 1v x 4d
    if (t < 256) {
        int v = t >> 2, d0 = (t & 3) * 4;
        float o4[4] = {};
        for (int ll = 0; ll < NL; ll += 4) {
            f4 S4 = *(const f4*)&s[v * 132 + ll];
            #pragma unroll
            for (int i2 = 0; i2 < 4; i2++)
                o4[i2] += dot4(S4, *(const f4*)&vhT[(d0 + i2) * 132 + ll]);
        }
        float* ob = osa + b * V * F + h * 16;
        float inv = 1.0f / rsum[v];
        #pragma unroll
        for (int i2 = 0; i2 < 4; i2++) ob[v * F + d0 + i2] = o4[i2] * inv;
    }
}

// ---------------- SelfAttentionFut, per (b,h) ----------------
__device__ void phase_saf(float* sm, const void* rwq, const void* rwk, const void* rwv,
                          const float* feat, int b, int h, int fl, float* osa) {
    int t = threadIdx.x;
    float* xs   = sm;            // 64*132
    float* wsl  = sm + 8448;     // 3*16*132
    float* qh   = sm + 14784;    // 64*20
    float* kh   = sm + 16064;    // 64*20
    float* vhT  = sm + 17344;    // 16*68
    float* s2   = sm + 18432;    // 64*68
    float* rsum = sm + 22784;    // 64

    const float* fb = feat + b * V * F;
    for (int i = t; i < 8192; i += 512) xs[(i >> 7) * 132 + (i & 127)] = fb[i];
    for (int i = t; i < 2048; i += 512) {
        int r = i >> 7, c = i & 127;
        wsl[0 * 2112 + r * 132 + c] = ldin(rwq, h * 2048 + i, fl);
        wsl[1 * 2112 + r * 132 + c] = ldin(rwk, h * 2048 + i, fl);
        wsl[2 * 2112 + r * 132 + c] = ldin(rwv, h * 2048 + i, fl);
    }
    __syncthreads();

    if (t < 256) {          // Q: 1v x 4d
        int v = t >> 2, d0 = (t & 3) * 4;
        float aq[4] = {};
        for (int kk = 0; kk < 128; kk += 4) {
            f4 X = *(const f4*)&xs[v * 132 + kk];
            #pragma unroll
            for (int i2 = 0; i2 < 4; i2++)
                aq[i2] += dot4(X, *(const f4*)&wsl[(d0 + i2) * 132 + kk]);
        }
        #pragma unroll
        for (int i2 = 0; i2 < 4; i2++) qh[v * 20 + d0 + i2] = aq[i2];
    } else if (t < 384) {   // K: 1v x 8d
        int tt = t - 256, v = tt >> 1, d0 = (tt & 1) * 8;
        float ak[8] = {};
        for (int kk = 0; kk < 128; kk += 4) {
            f4 X = *(const f4*)&xs[v * 132 + kk];
            #pragma unroll
            for (int i2 = 0; i2 < 8; i2++)
                ak[i2] += dot4(X, *(const f4*)&wsl[2112 + (d0 + i2) * 132 + kk]);
        }
        #pragma unroll
        for (int i2 = 0; i2 < 8; i2++) kh[v * 20 + d0 + i2] = ak[i2];
    } else {                // V -> transposed
        int tt = t - 384, v = tt >> 1, d0 = (tt & 1) * 8;
        float av[8] = {};
        for (int kk = 0; kk < 128; kk += 4) {
            f4 X = *(const f4*)&xs[v * 132 + kk];
            #pragma unroll
            for (int i2 = 0; i2 < 8; i2++)
                av[i2] += dot4(X, *(const f4*)&wsl[4224 + (d0 + i2) * 132 + kk]);
        }
        #pragma unroll
        for (int i2 = 0; i2 < 8; i2++) vhT[(d0 + i2) * 68 + v] = av[i2];
    }
    __syncthreads();

    {   // scores 64x64: all 512 thr, 4x2 tiles
        int v0 = t >> 5, l0 = t & 31;
        float sc[4][2] = {};
        #pragma unroll
        for (int kd = 0; kd < 16; kd += 4) {
            f4 Q[4], K2[2];
            #pragma unroll
            for (int m = 0; m < 4; m++) Q[m] = *(const f4*)&qh[(v0 + 16 * m) * 20 + kd];
            #pragma unroll
            for (int i2 = 0; i2 < 2; i2++) K2[i2] = *(const f4*)&kh[(l0 + 32 * i2) * 20 + kd];
            #pragma unroll
            for (int m = 0; m < 4; m++)
                #pragma unroll
                for (int i2 = 0; i2 < 2; i2++) sc[m][i2] += dot4(Q[m], K2[i2]);
        }
        #pragma unroll
        for (int m = 0; m < 4; m++)
            #pragma unroll
            for (int i2 = 0; i2 < 2; i2++)
                s2[(v0 + 16 * m) * 68 + l0 + 32 * i2] = sc[m][i2] * 0.25f;
    }
    __syncthreads();

    {   // softmax over 64
        int v = t >> 3, j = t & 7;
        float* sr = s2 + v * 68;
        float m = -1e30f;
        for (int k = j; k < V; k += 8) m = fmaxf(m, sr[k]);
        for (int off = 1; off < 8; off <<= 1) m = fmaxf(m, __shfl_xor(m, off));
        float sum = 0.f;
        for (int k = j; k < V; k += 8) { float e = __expf(sr[k] - m); sr[k] = e; sum += e; }
        for (int off = 1; off < 8; off <<= 1) sum += __shfl_xor(sum, off);
        if (j == 0) rsum[v] = sum;
    }
    __syncthreads();

    if (t < 256) {          // PV
        int v = t >> 2, d0 = (t & 3) * 4;
        float o4[4] = {};
        for (int ll = 0; ll < V; ll += 4) {
            f4 S4 = *(const f4*)&s2[v * 68 + ll];
            #pragma unroll
            for (int i2 = 0; i2 < 4; i2++)
                o4[i2] += dot4(S4, *(const f4*)&vhT[(d0 + i2) * 68 + ll]);
        }
        float* ob = osa + b * V * F + h * 16;
        float inv = 1.0f / rsum[v];
        #pragma unroll
        for (int i2 = 0; i2 < 4; i2++) ob[v * F + d0 + i2] = o4[i2] * inv;
    }
}

// ---------------- projres: feat = osa @ wcT + res, 8 bv per block ----------------
__device__ void phase_projres(float* sm, const float* ws, const float* osa,
                              const void* rinp, int wc_off, int mode,
                              float* feat, int bid, int fl) {
    int t = threadIdx.x;
    int bvl = t >> 6, tt = t & 63;
    int bv = bid * 8 + bvl;
    float* orow = sm + bvl * 128;
    orow[tt] = osa[bv * 128 + tt];
    orow[tt + 64] = osa[bv * 128 + tt + 64];
    __syncthreads();
    const float* wcT = ws + wc_off;
    float a0 = 0.f, a1 = 0.f;
    for (int k = 0; k < 128; k++) {
        float x = orow[k];
        a0 += x * wcT[k * 128 + tt];
        a1 += x * wcT[k * 128 + tt + 64];
    }
    float r0, r1;
    if (mode == 0) {
        int b = bv >> 6, v = bv & 63;
        float i00 = ldin(rinp, ((b * 2 + 0) * 64 + v) * 20 + 18, fl);
        float i01 = ldin(rinp, ((b * 2 + 0) * 64 + v) * 20 + 19, fl);
        float i10 = ldin(rinp, ((b * 2 + 1) * 64 + v) * 20 + 18, fl);
        float i11 = ldin(rinp, ((b * 2 + 1) * 64 + v) * 20 + 19, fl);
        const float* ew = ws + OFF_EMBW;
        r0 = ws[OFF_EMBB + tt] + i00 * ew[tt * 6 + 0] + i01 * ew[tt * 6 + 1]
           + i10 * ew[tt * 6 + 3] + i11 * ew[tt * 6 + 4];
        int u2 = tt + 64;
        r1 = ws[OFF_EMBB + u2] + i00 * ew[u2 * 6 + 0] + i01 * ew[u2 * 6 + 1]
           + i10 * ew[u2 * 6 + 3] + i11 * ew[u2 * 6 + 4];
    } else {
        r0 = feat[bv * 128 + tt];
        r1 = feat[bv * 128 + tt + 64];
    }
    feat[bv * 128 + tt] = a0 + r0;
    feat[bv * 128 + tt + 64] = a1 + r1;
}

// ---------------- output head + activation + direct broadcast write ----------------
__device__ void phase_out(float* sm, const float* ws, const float* ola,
                          const float* feat, const void* rpos, void* out,
                          int bid, int fl) {
    int t = threadIdx.x;
    int bvl = t >> 6, tt = t & 63;
    int bv = bid * 8 + bvl;
    float* orow = sm + bvl * 128;
    float* h3   = sm + 1024 + bvl * 128;
    float* z1   = sm + 2048 + bvl * 128;
    float* z2   = sm + 3072 + bvl * 128;
    float* z3all = sm + 4096;               // [8][40]
    float* z3   = z3all + bvl * 40;
    orow[tt] = ola[bv * 128 + tt];
    orow[tt + 64] = ola[bv * 128 + tt + 64];
    __syncthreads();
    const float* wclaT = ws + WCLA_T;
    float a0 = 0.f, a1 = 0.f;
    for (int k = 0; k < 128; k++) {
        float x = orow[k];
        a0 += x * wclaT[k * 128 + tt]; a1 += x * wclaT[k * 128 + tt + 64];
    }
    h3[tt] = a0 + feat[bv * 128 + tt];
    h3[tt + 64] = a1 + feat[bv * 128 + tt + 64];
    __syncthreads();
    const float* w1T = ws + W1_T;
    a0 = ws[OFF_B1 + tt]; a1 = ws[OFF_B1 + tt + 64];
    for (int k = 0; k < 128; k++) {
        float x = h3[k];
        a0 += x * w1T[k * 128 + tt]; a1 += x * w1T[k * 128 + tt + 64];
    }
    z1[tt] = fmaxf(a0, 0.f); z1[tt + 64] = fmaxf(a1, 0.f);
    __syncthreads();
    const float* w2T = ws + W2_T;
    a0 = ws[OFF_B2 + tt]; a1 = ws[OFF_B2 + tt + 64];
    for (int k = 0; k < 128; k++) {
        float x = z1[k];
        a0 += x * w2T[k * 128 + tt]; a1 += x * w2T[k * 128 + tt + 64];
    }
    z2[tt] = fmaxf(a0, 0.f); z2[tt + 64] = fmaxf(a1, 0.f);
    __syncthreads();
    const float* woT = ws + WO_T;
    if (tt < 36) {
        float a = ws[OFF_BO + tt];
        for (int k = 0; k < 128; k++) a += z2[k] * woT[k * 36 + tt];
        z3[tt] = a;
    }
    __syncthreads();
    float r = 0.f;
    if (tt < 36) {
        int c = tt % 6;
        float xv = z3[tt];
        if (c == 0)      r = xv + ldin(rpos, bv * 2 + 0, fl);
        else if (c == 1) r = xv + ldin(rpos, bv * 2 + 1, fl);
        else if (c == 2 || c == 3) r = __expf(0.5f * xv);
        else if (c == 4) r = tanhf(xv);
        else {
            const float inv = 0.4082482904638631f;  // 1/sqrt(6)
            float m = -1e30f;
            for (int pp = 0; pp < 6; pp++) m = fmaxf(m, z3[pp * 6 + 5] * inv);
            float sum = 0.f;
            for (int pp = 0; pp < 6; pp++) sum += __expf(z3[pp * 6 + 5] * inv - m);
            r = __expf(xv * inv - m) / sum;
        }
    }
    __syncthreads();
    if (tt < 36) z3[tt] = r;
    __syncthreads();
    // block writes 8 bv x 36 = 288 contiguous elements per timestep
    int base = bid * 288;
    if (fl) {
        float* o = (float*)out;
        for (int i = t; i < LEN_PRED * 288; i += 512) {
            int ttp = i / 288, idx = i - ttp * 288;
            o[ttp * 73728 + base + idx] = z3all[(idx / 36) * 40 + idx % 36];
        }
    } else {
        bf16* o = (bf16*)out;
        for (int i = t; i < LEN_PRED * 288; i += 512) {
            int ttp = i / 288, idx = i - ttp * 288;
            o[ttp * 73728 + base + idx] = __float2bfloat16(z3all[(idx / 36) * 40 + idx % 36]);
        }
    }
}

// ---------------- fused persistent kernel: 256 blocks x 512 thr ----------------
__global__ __launch_bounds__(512) void k_fused(InPtrs ptrs, float* __restrict__ ws,
                                               void* __restrict__ out) {
    int bid = blockIdx.x;
    int b = bid >> 3, h = bid & 7;
    int fl = detect_f32(ptrs.p[1], threadIdx.x);
    int* flags = (int*)(ws + OFF_BAR);
    int* gen   = flags + 256 * 32;
    float* feat = ws + OFF_FEAT;
    float* osa  = ws + OFF_OSA;
    __shared__ __align__(16) float sm[27712];   // ~110.8 KB -> 1 block/CU

    // P1: LaneAttentionPast (+ weight prep on blocks 245..255; P1 doesn't use ws weights)
    phase_attn_lane(sm, ptrs.p[5], ptrs.p[6], ptrs.p[7], ptrs.p[1], ptrs.p[0],
                    ptrs.p[3], ptrs.p[4], nullptr, 1, b, h, fl, osa);
    __syncthreads();
    if (bid >= 245) phase_prep(sm, ptrs, fl, ws, bid - 245);
    grid_bar(flags, gen, bid, 1);
    // P2: feat = emb + osa @ wcP^T
    phase_projres(sm, ws, osa, ptrs.p[0], WCP_T, 0, feat, bid, fl);
    grid_bar(flags, gen, bid, 2);
    // P3: SelfAttentionFut
    phase_saf(sm, ptrs.p[10], ptrs.p[9], ptrs.p[11], feat, b, h, fl, osa);
    grid_bar(flags, gen, bid, 3);
    // P4: feat += osa @ wcSA^T
    phase_projres(sm, ws, osa, ptrs.p[0], WCSA_T, 1, feat, bid, fl);
    grid_bar(flags, gen, bid, 4);
    // P5: LaneAttentionFut
    phase_attn_lane(sm, ptrs.p[15], ptrs.p[13], ptrs.p[14], ptrs.p[1], ptrs.p[0],
                    ptrs.p[3], ptrs.p[4], feat, 0, b, h, fl, osa);
    grid_bar(flags, gen, bid, 5);
    // P6: output head + activation + broadcast write
    phase_out(sm, ws, osa, feat, ptrs.p[2], out, bid, fl);
}

extern "C" void kernel_launch(void* const* d_in, const int* in_sizes, int n_in,
                              void* d_out, int out_size, void* d_ws, size_t ws_size,
                              hipStream_t stream) {
    float* ws = (float*)d_ws;
    // zero flags (256*32 ints) + gen (ws is poisoned 0xAA); capture-legal async memset
    hipMemsetAsync((char*)d_ws + (size_t)OFF_BAR * 4, 0, 256 * 32 * 4 + 64, stream);
    InPtrs ptrs;
    for (int i = 0; i < 23; i++) ptrs.p[i] = d_in[i];
    k_fused<<<256, 512, 0, stream>>>(ptrs, ws, d_out);
}

// Round 9
// 125.097 us; speedup vs baseline: 2.3183x; 1.2634x over previous
//
#include <hip/hip_runtime.h>
#include <hip/hip_bf16.h>
#include <math.h>

typedef __hip_bfloat16 bf16;
typedef float4 f4;

#define B 32
#define V 64
#define F 128
#define NL 128
#define H 8
#define DH 16
#define LEN_PRED 30

// ---- f32 workspace layout (element offsets) ----
#define OFF_EMBW 0
#define OFF_EMBB 768
#define OFF_B1   896
#define OFF_B2   1024
#define OFF_BO   1152
#define WCP_T    1216
#define WCSA_T   17600
#define WCLA_T   33984
#define W1_T     50368
#define W2_T     66752
#define WO_T     83136
#define OFF_FEAT1 87744
#define OFF_FEAT2 349888
#define OFF_OSA1  612032
#define OFF_OSA2  874176

struct InPtrs { const void* p[23]; };

__device__ __forceinline__ float dot4(f4 a, f4 b) {
    return a.x * b.x + a.y * b.y + a.z * b.z + a.w * b.w;
}

// dtype detect: f32 read as u16 pairs has wild exponents in mantissa halves;
// bf16 N(0,1) never does. Uniform across all waves.
__device__ __forceinline__ int detect_f32(const void* lanesraw, int t) {
    const unsigned short* u = (const unsigned short*)lanesraw;
    int lane = t & 63;
    int wild = 0;
    for (int j = 0; j < 4; j++) {
        int e = (u[lane * 4 + j] >> 7) & 0xFF;
        if (e != 0 && (e < 90 || e > 164)) wild++;
    }
    unsigned long long m = __ballot(wild > 0);
    return (__popcll(m) >= 16) ? 1 : 0;
}

__device__ __forceinline__ float ldin(const void* p, int i, int fl) {
    return fl ? ((const float*)p)[i] : __bfloat162float(((const bf16*)p)[i]);
}

// ---------------- prep: vec copies + 6 weight transposes ----------------
__device__ void phase_prep(float* sm, const InPtrs& ptrs, int fl, float* ws, int seg) {
    const int srci[11] = {3, 4, 18, 20, 22, 8, 12, 16, 17, 19, 21};
    const int szs[11]  = {768, 128, 128, 128, 36, 16384, 16384, 16384, 16384, 16384, 4608};
    const int dsto[11] = {OFF_EMBW, OFF_EMBB, OFF_B1, OFF_B2, OFF_BO,
                          WCP_T, WCSA_T, WCLA_T, W1_T, W2_T, WO_T};
    const int Otab[11] = {0, 0, 0, 0, 0, 128, 128, 128, 128, 128, 36};
    int t = threadIdx.x;
    int n = szs[seg], O = Otab[seg];
    const void* src = ptrs.p[srci[seg]];
    if (O == 0) {
        for (int i = t; i < n; i += 512) ws[dsto[seg] + i] = ldin(src, i, fl);
        return;
    }
    float* tile = sm;                       // 128*129 = 16512 floats
    for (int i = t; i < n; i += 512) {
        int o = i >> 7, k = i & 127;
        tile[o * 129 + k] = ldin(src, i, fl);
    }
    __syncthreads();
    float* dst = ws + dsto[seg];
    for (int j = t; j < n; j += 512) {
        int k = j / O, o = j - k * O;
        dst[j] = tile[o * 129 + k];
    }
}

// ---------------- K1: LaneAttentionPast (x = embedding), per (b,h) ----------------
__device__ void phase_attn_lane_past(float* sm, const InPtrs& ptrs,
                                     int b, int h, int fl, float* osa) {
    int t = threadIdx.x;
    float* ln   = sm;            // 128*68 (aliased by scores later)
    float* xs   = sm + 8704;     // 64*132
    float* wql  = sm + 17152;    // 16*132
    float* wkl  = sm + 19264;    // 16*68
    float* wvl  = sm + 20352;    // 16*68
    float* kh   = sm + 21440;    // 128*20
    float* vhT  = sm + 24000;    // 16*132
    float* qh   = sm + 26112;    // 64*20
    float* rsum = sm + 27392;    // 64
    float* in4  = sm + 27456;    // 256
    float* s    = ln;

    int lb = b * NL * 64;
    for (int i = t; i < NL * 64; i += 512)
        ln[(i >> 6) * 68 + (i & 63)] = ldin(ptrs.p[1], lb + i, fl);
    for (int i = t; i < 2048; i += 512)
        wql[(i >> 7) * 132 + (i & 127)] = ldin(ptrs.p[5], h * 2048 + i, fl);
    for (int i = t; i < 1024; i += 512)
        wkl[(i >> 6) * 68 + (i & 63)] = ldin(ptrs.p[6], h * 1024 + i, fl);
    for (int i = t; i < 1024; i += 512)
        wvl[(i >> 6) * 68 + (i & 63)] = ldin(ptrs.p[7], h * 1024 + i, fl);
    if (t < 64) {
        in4[t * 4 + 0] = ldin(ptrs.p[0], ((b * 2 + 0) * 64 + t) * 20 + 18, fl);
        in4[t * 4 + 1] = ldin(ptrs.p[0], ((b * 2 + 0) * 64 + t) * 20 + 19, fl);
        in4[t * 4 + 2] = ldin(ptrs.p[0], ((b * 2 + 1) * 64 + t) * 20 + 18, fl);
        in4[t * 4 + 3] = ldin(ptrs.p[0], ((b * 2 + 1) * 64 + t) * 20 + 19, fl);
    }
    __syncthreads();
    for (int i = t; i < 8192; i += 512) {
        int v = i >> 7, c = i & 127;
        xs[v * 132 + c] = ldin(ptrs.p[4], c, fl)
            + in4[v * 4 + 0] * ldin(ptrs.p[3], c * 6 + 0, fl)
            + in4[v * 4 + 1] * ldin(ptrs.p[3], c * 6 + 1, fl)
            + in4[v * 4 + 2] * ldin(ptrs.p[3], c * 6 + 3, fl)
            + in4[v * 4 + 3] * ldin(ptrs.p[3], c * 6 + 4, fl);
    }
    __syncthreads();

    // proj: t<256 -> K,V ; t>=256 -> Q
    if (t < 256) {
        int l0 = t >> 3, d0 = (t & 7) * 2;
        float ak[4][2] = {}, av[4][2] = {};
        for (int kk = 0; kk < 64; kk += 4) {
            f4 L[4], WK[2], WV[2];
            #pragma unroll
            for (int m = 0; m < 4; m++) L[m] = *(const f4*)&ln[(l0 + 32 * m) * 68 + kk];
            #pragma unroll
            for (int j = 0; j < 2; j++) {
                WK[j] = *(const f4*)&wkl[(d0 + j) * 68 + kk];
                WV[j] = *(const f4*)&wvl[(d0 + j) * 68 + kk];
            }
            #pragma unroll
            for (int m = 0; m < 4; m++)
                #pragma unroll
                for (int j = 0; j < 2; j++) {
                    ak[m][j] += dot4(L[m], WK[j]);
                    av[m][j] += dot4(L[m], WV[j]);
                }
        }
        #pragma unroll
        for (int m = 0; m < 4; m++)
            #pragma unroll
            for (int j = 0; j < 2; j++) {
                int l = l0 + 32 * m, d = d0 + j;
                kh[l * 20 + d] = ak[m][j];
                vhT[d * 132 + l] = av[m][j];
            }
    } else {
        int tt = t - 256, v = tt >> 2, d0 = (tt & 3) * 4;
        float aq[4] = {};
        for (int kk = 0; kk < 128; kk += 4) {
            f4 X = *(const f4*)&xs[v * 132 + kk];
            #pragma unroll
            for (int i2 = 0; i2 < 4; i2++)
                aq[i2] += dot4(X, *(const f4*)&wql[(d0 + i2) * 132 + kk]);
        }
        #pragma unroll
        for (int i2 = 0; i2 < 4; i2++) qh[v * 20 + d0 + i2] = aq[i2];
    }
    __syncthreads();

    {   // scores: 4x4 tiles -> s (dead ln)
        int v0 = t >> 5, l0 = t & 31;
        float sc[4][4] = {};
        #pragma unroll
        for (int kd = 0; kd < 16; kd += 4) {
            f4 Q[4], K4[4];
            #pragma unroll
            for (int m = 0; m < 4; m++) Q[m] = *(const f4*)&qh[(v0 + 16 * m) * 20 + kd];
            #pragma unroll
            for (int i2 = 0; i2 < 4; i2++) K4[i2] = *(const f4*)&kh[(l0 + 32 * i2) * 20 + kd];
            #pragma unroll
            for (int m = 0; m < 4; m++)
                #pragma unroll
                for (int i2 = 0; i2 < 4; i2++) sc[m][i2] += dot4(Q[m], K4[i2]);
        }
        #pragma unroll
        for (int m = 0; m < 4; m++)
            #pragma unroll
            for (int i2 = 0; i2 < 4; i2++)
                s[(v0 + 16 * m) * 132 + l0 + 32 * i2] = sc[m][i2] * 0.25f;
    }
    __syncthreads();

    {   // softmax, 8 lanes/row
        int v = t >> 3, j = t & 7;
        float* sr = s + v * 132;
        float m = -1e30f;
        for (int k = j; k < NL; k += 8) m = fmaxf(m, sr[k]);
        for (int off = 1; off < 8; off <<= 1) m = fmaxf(m, __shfl_xor(m, off));
        float sum = 0.f;
        for (int k = j; k < NL; k += 8) { float e = __expf(sr[k] - m); sr[k] = e; sum += e; }
        for (int off = 1; off < 8; off <<= 1) sum += __shfl_xor(sum, off);
        if (j == 0) rsum[v] = sum;
    }
    __syncthreads();

    if (t < 256) {   // PV
        int v = t >> 2, d0 = (t & 3) * 4;
        float o4[4] = {};
        for (int ll = 0; ll < NL; ll += 4) {
            f4 S4 = *(const f4*)&s[v * 132 + ll];
            #pragma unroll
            for (int i2 = 0; i2 < 4; i2++)
                o4[i2] += dot4(S4, *(const f4*)&vhT[(d0 + i2) * 132 + ll]);
        }
        float* ob = osa + b * 8192 + h * 16;
        float inv = 1.0f / rsum[v];
        #pragma unroll
        for (int i2 = 0; i2 < 4; i2++) ob[v * F + d0 + i2] = o4[i2] * inv;
    }
}

__global__ __launch_bounds__(512) void k1_lap(InPtrs ptrs, float* __restrict__ ws) {
    int bid = blockIdx.x, b = bid >> 3, h = bid & 7, t = threadIdx.x;
    int fl = detect_f32(ptrs.p[1], t);
    __shared__ __align__(16) float sm[27712];
    phase_attn_lane_past(sm, ptrs, b, h, fl, ws + OFF_OSA1);
    __syncthreads();
    if (bid >= 245) phase_prep(sm, ptrs, fl, ws, bid - 245);
}

// ---------------- K2: feat1 = emb + osa1@wcP^T (in-block), SelfAttentionFut ----------------
__global__ __launch_bounds__(512) void k2_saf(InPtrs ptrs, float* __restrict__ ws) {
    int bid = blockIdx.x, b = bid >> 3, h = bid & 7, t = threadIdx.x;
    int fl = detect_f32(ptrs.p[1], t);
    __shared__ __align__(16) float smem[23488];   // 94 KB
    float* osap = smem;            // 8448 (dead after feat1) -> qh/kh/vhT/s2/rsum
    float* qh   = smem;            // 1280
    float* kh   = smem + 1280;     // 1280
    float* vhT  = smem + 2560;     // 1088
    float* s2   = smem + 3648;     // 4352
    float* rsum = smem + 8000;     // 64
    float* xs   = smem + 8448;     // 8448
    float* wsl  = smem + 16896;    // 6336
    float* in4  = smem + 23232;    // 256

    const float* o1 = ws + OFF_OSA1 + b * 8192;
    for (int i = t; i < 8192; i += 512) osap[(i >> 7) * 132 + (i & 127)] = o1[i];
    for (int i = t; i < 2048; i += 512) {
        int r = i >> 7, c = i & 127;
        wsl[r * 132 + c]        = ldin(ptrs.p[10], h * 2048 + i, fl);  // wq_fut_sa
        wsl[2112 + r * 132 + c] = ldin(ptrs.p[9],  h * 2048 + i, fl);  // wk_fut
        wsl[4224 + r * 132 + c] = ldin(ptrs.p[11], h * 2048 + i, fl);  // wv_fut
    }
    if (t < 64) {
        in4[t * 4 + 0] = ldin(ptrs.p[0], ((b * 2 + 0) * 64 + t) * 20 + 18, fl);
        in4[t * 4 + 1] = ldin(ptrs.p[0], ((b * 2 + 0) * 64 + t) * 20 + 19, fl);
        in4[t * 4 + 2] = ldin(ptrs.p[0], ((b * 2 + 1) * 64 + t) * 20 + 18, fl);
        in4[t * 4 + 3] = ldin(ptrs.p[0], ((b * 2 + 1) * 64 + t) * 20 + 19, fl);
    }
    __syncthreads();
    // emb into xs
    for (int i = t; i < 8192; i += 512) {
        int v = i >> 7, c = i & 127;
        xs[v * 132 + c] = ldin(ptrs.p[4], c, fl)
            + in4[v * 4 + 0] * ldin(ptrs.p[3], c * 6 + 0, fl)
            + in4[v * 4 + 1] * ldin(ptrs.p[3], c * 6 + 1, fl)
            + in4[v * 4 + 2] * ldin(ptrs.p[3], c * 6 + 3, fl)
            + in4[v * 4 + 3] * ldin(ptrs.p[3], c * 6 + 4, fl);
    }
    __syncthreads();
    // xs += osap @ wcpT  (4v x 4c per thread)
    {
        const float* wT = ws + WCP_T;
        int v0 = (t >> 5) * 4, c0 = (t & 31) * 4;
        float acc[4][4];
        #pragma unroll
        for (int m = 0; m < 4; m++) {
            f4 X0 = *(const f4*)&xs[(v0 + m) * 132 + c0];
            acc[m][0] = X0.x; acc[m][1] = X0.y; acc[m][2] = X0.z; acc[m][3] = X0.w;
        }
        for (int k = 0; k < 128; k += 4) {
            f4 W0 = *(const f4*)&wT[(k + 0) * 128 + c0];
            f4 W1 = *(const f4*)&wT[(k + 1) * 128 + c0];
            f4 W2 = *(const f4*)&wT[(k + 2) * 128 + c0];
            f4 W3 = *(const f4*)&wT[(k + 3) * 128 + c0];
            #pragma unroll
            for (int m = 0; m < 4; m++) {
                f4 X = *(const f4*)&osap[(v0 + m) * 132 + k];
                acc[m][0] += X.x * W0.x + X.y * W1.x + X.z * W2.x + X.w * W3.x;
                acc[m][1] += X.x * W0.y + X.y * W1.y + X.z * W2.y + X.w * W3.y;
                acc[m][2] += X.x * W0.z + X.y * W1.z + X.z * W2.z + X.w * W3.z;
                acc[m][3] += X.x * W0.w + X.y * W1.w + X.z * W2.w + X.w * W3.w;
            }
        }
        #pragma unroll
        for (int m = 0; m < 4; m++)
            *(f4*)&xs[(v0 + m) * 132 + c0] =
                make_float4(acc[m][0], acc[m][1], acc[m][2], acc[m][3]);
    }
    __syncthreads();
    if (h == 0) {
        float* f1 = ws + OFF_FEAT1 + b * 8192;
        for (int i = t; i < 8192; i += 512) f1[i] = xs[(i >> 7) * 132 + (i & 127)];
    }
    // NOTE: qh/kh/vhT alias osap — all osap reads completed before this sync
    __syncthreads();

    if (t < 256) {          // Q: 1v x 4d
        int v = t >> 2, d0 = (t & 3) * 4;
        float aq[4] = {};
        for (int kk = 0; kk < 128; kk += 4) {
            f4 X = *(const f4*)&xs[v * 132 + kk];
            #pragma unroll
            for (int i2 = 0; i2 < 4; i2++)
                aq[i2] += dot4(X, *(const f4*)&wsl[(d0 + i2) * 132 + kk]);
        }
        #pragma unroll
        for (int i2 = 0; i2 < 4; i2++) qh[v * 20 + d0 + i2] = aq[i2];
    } else if (t < 384) {   // K: 1v x 8d
        int tt = t - 256, v = tt >> 1, d0 = (tt & 1) * 8;
        float ak[8] = {};
        for (int kk = 0; kk < 128; kk += 4) {
            f4 X = *(const f4*)&xs[v * 132 + kk];
            #pragma unroll
            for (int i2 = 0; i2 < 8; i2++)
                ak[i2] += dot4(X, *(const f4*)&wsl[2112 + (d0 + i2) * 132 + kk]);
        }
        #pragma unroll
        for (int i2 = 0; i2 < 8; i2++) kh[v * 20 + d0 + i2] = ak[i2];
    } else {                // V -> transposed
        int tt = t - 384, v = tt >> 1, d0 = (tt & 1) * 8;
        float av[8] = {};
        for (int kk = 0; kk < 128; kk += 4) {
            f4 X = *(const f4*)&xs[v * 132 + kk];
            #pragma unroll
            for (int i2 = 0; i2 < 8; i2++)
                av[i2] += dot4(X, *(const f4*)&wsl[4224 + (d0 + i2) * 132 + kk]);
        }
        #pragma unroll
        for (int i2 = 0; i2 < 8; i2++) vhT[(d0 + i2) * 68 + v] = av[i2];
    }
    __syncthreads();

    {   // scores 64x64: 4x2 tiles
        int v0 = t >> 5, l0 = t & 31;
        float sc[4][2] = {};
        #pragma unroll
        for (int kd = 0; kd < 16; kd += 4) {
            f4 Q[4], K2[2];
            #pragma unroll
            for (int m = 0; m < 4; m++) Q[m] = *(const f4*)&qh[(v0 + 16 * m) * 20 + kd];
            #pragma unroll
            for (int i2 = 0; i2 < 2; i2++) K2[i2] = *(const f4*)&kh[(l0 + 32 * i2) * 20 + kd];
            #pragma unroll
            for (int m = 0; m < 4; m++)
                #pragma unroll
                for (int i2 = 0; i2 < 2; i2++) sc[m][i2] += dot4(Q[m], K2[i2]);
        }
        #pragma unroll
        for (int m = 0; m < 4; m++)
            #pragma unroll
            for (int i2 = 0; i2 < 2; i2++)
                s2[(v0 + 16 * m) * 68 + l0 + 32 * i2] = sc[m][i2] * 0.25f;
    }
    __syncthreads();

    {   // softmax over 64
        int v = t >> 3, j = t & 7;
        float* sr = s2 + v * 68;
        float m = -1e30f;
        for (int k = j; k < V; k += 8) m = fmaxf(m, sr[k]);
        for (int off = 1; off < 8; off <<= 1) m = fmaxf(m, __shfl_xor(m, off));
        float sum = 0.f;
        for (int k = j; k < V; k += 8) { float e = __expf(sr[k] - m); sr[k] = e; sum += e; }
        for (int off = 1; off < 8; off <<= 1) sum += __shfl_xor(sum, off);
        if (j == 0) rsum[v] = sum;
    }
    __syncthreads();

    if (t < 256) {          // PV
        int v = t >> 2, d0 = (t & 3) * 4;
        float o4[4] = {};
        for (int ll = 0; ll < V; ll += 4) {
            f4 S4 = *(const f4*)&s2[v * 68 + ll];
            #pragma unroll
            for (int i2 = 0; i2 < 4; i2++)
                o4[i2] += dot4(S4, *(const f4*)&vhT[(d0 + i2) * 68 + ll]);
        }
        float* ob = ws + OFF_OSA2 + b * 8192 + h * 16;
        float inv = 1.0f / rsum[v];
        #pragma unroll
        for (int i2 = 0; i2 < 4; i2++) ob[v * F + d0 + i2] = o4[i2] * inv;
    }
}

// ---------------- K3: feat2 = feat1 + osa2@wcSA^T (in-block), LaneAttentionFut ----------------
__global__ __launch_bounds__(512) void k3_laf(InPtrs ptrs, float* __restrict__ ws) {
    int bid = blockIdx.x, b = bid >> 3, h = bid & 7, t = threadIdx.x;
    int fl = detect_f32(ptrs.p[1], t);
    __shared__ __align__(16) float smem[29888];   // 119.5 KB
    float* ln   = smem;            // 8704 (scores alias)
    float* osas = smem + 8704;     // 8448 (dead after feat2) -> kh/vhT/qh/rsum
    float* kh   = smem + 8704;     // 2560
    float* vhT  = smem + 11264;    // 2112
    float* qh   = smem + 13376;    // 1280
    float* rsum = smem + 14656;    // 64
    float* xs   = smem + 17152;    // 8448
    float* wql  = smem + 25600;    // 2112
    float* wkl  = smem + 27712;    // 1088
    float* wvl  = smem + 28800;    // 1088
    float* s    = ln;

    int lb = b * NL * 64;
    for (int i = t; i < NL * 64; i += 512)
        ln[(i >> 6) * 68 + (i & 63)] = ldin(ptrs.p[1], lb + i, fl);
    const float* o2 = ws + OFF_OSA2 + b * 8192;
    for (int i = t; i < 8192; i += 512) osas[(i >> 7) * 132 + (i & 127)] = o2[i];
    for (int i = t; i < 2048; i += 512)
        wql[(i >> 7) * 132 + (i & 127)] = ldin(ptrs.p[15], h * 2048 + i, fl);
    for (int i = t; i < 1024; i += 512)
        wkl[(i >> 6) * 68 + (i & 63)] = ldin(ptrs.p[13], h * 1024 + i, fl);
    for (int i = t; i < 1024; i += 512)
        wvl[(i >> 6) * 68 + (i & 63)] = ldin(ptrs.p[14], h * 1024 + i, fl);
    __syncthreads();
    // xs = feat1 + osas @ wcsaT  (4v x 4c per thread)
    {
        const float* wT = ws + WCSA_T;
        const float* f1 = ws + OFF_FEAT1 + b * 8192;
        int v0 = (t >> 5) * 4, c0 = (t & 31) * 4;
        float acc[4][4];
        #pragma unroll
        for (int m = 0; m < 4; m++) {
            f4 X0 = *(const f4*)&f1[(v0 + m) * 128 + c0];
            acc[m][0] = X0.x; acc[m][1] = X0.y; acc[m][2] = X0.z; acc[m][3] = X0.w;
        }
        for (int k = 0; k < 128; k += 4) {
            f4 W0 = *(const f4*)&wT[(k + 0) * 128 + c0];
            f4 W1 = *(const f4*)&wT[(k + 1) * 128 + c0];
            f4 W2 = *(const f4*)&wT[(k + 2) * 128 + c0];
            f4 W3 = *(const f4*)&wT[(k + 3) * 128 + c0];
            #pragma unroll
            for (int m = 0; m < 4; m++) {
                f4 X = *(const f4*)&osas[(v0 + m) * 132 + k];
                acc[m][0] += X.x * W0.x + X.y * W1.x + X.z * W2.x + X.w * W3.x;
                acc[m][1] += X.x * W0.y + X.y * W1.y + X.z * W2.y + X.w * W3.y;
                acc[m][2] += X.x * W0.z + X.y * W1.z + X.z * W2.z + X.w * W3.z;
                acc[m][3] += X.x * W0.w + X.y * W1.w + X.z * W2.w + X.w * W3.w;
            }
        }
        #pragma unroll
        for (int m = 0; m < 4; m++)
            *(f4*)&xs[(v0 + m) * 132 + c0] =
                make_float4(acc[m][0], acc[m][1], acc[m][2], acc[m][3]);
    }
    __syncthreads();
    if (h == 0) {
        float* f2 = ws + OFF_FEAT2 + b * 8192;
        for (int i = t; i < 8192; i += 512) f2[i] = xs[(i >> 7) * 132 + (i & 127)];
    }
    __syncthreads();   // osas reads done; kh/vhT/qh (alias) writes may begin

    // proj: t<256 -> K,V from lanes; t>=256 -> Q from xs
    if (t < 256) {
        int l0 = t >> 3, d0 = (t & 7) * 2;
        float ak[4][2] = {}, av[4][2] = {};
        for (int kk = 0; kk < 64; kk += 4) {
            f4 L[4], WK[2], WV[2];
            #pragma unroll
            for (int m = 0; m < 4; m++) L[m] = *(const f4*)&ln[(l0 + 32 * m) * 68 + kk];
            #pragma unroll
            for (int j = 0; j < 2; j++) {
                WK[j] = *(const f4*)&wkl[(d0 + j) * 68 + kk];
                WV[j] = *(const f4*)&wvl[(d0 + j) * 68 + kk];
            }
            #pragma unroll
            for (int m = 0; m < 4; m++)
                #pragma unroll
                for (int j = 0; j < 2; j++) {
                    ak[m][j] += dot4(L[m], WK[j]);
                    av[m][j] += dot4(L[m], WV[j]);
                }
        }
        #pragma unroll
        for (int m = 0; m < 4; m++)
            #pragma unroll
            for (int j = 0; j < 2; j++) {
                int l = l0 + 32 * m, d = d0 + j;
                kh[l * 20 + d] = ak[m][j];
                vhT[d * 132 + l] = av[m][j];
            }
    } else {
        int tt = t - 256, v = tt >> 2, d0 = (tt & 3) * 4;
        float aq[4] = {};
        for (int kk = 0; kk < 128; kk += 4) {
            f4 X = *(const f4*)&xs[v * 132 + kk];
            #pragma unroll
            for (int i2 = 0; i2 < 4; i2++)
                aq[i2] += dot4(X, *(const f4*)&wql[(d0 + i2) * 132 + kk]);
        }
        #pragma unroll
        for (int i2 = 0; i2 < 4; i2++) qh[v * 20 + d0 + i2] = aq[i2];
    }
    __syncthreads();

    {   // scores 64x128: 4x4 tiles -> s (dead ln)
        int v0 = t >> 5, l0 = t & 31;
        float sc[4][4] = {};
        #pragma unroll
        for (int kd = 0; kd < 16; kd += 4) {
            f4 Q[4], K4[4];
            #pragma unroll
            for (int m = 0; m < 4; m++) Q[m] = *(const f4*)&qh[(v0 + 16 * m) * 20 + kd];
            #pragma unroll
            for (int i2 = 0; i2 < 4; i2++) K4[i2] = *(const f4*)&kh[(l0 + 32 * i2) * 20 + kd];
            #pragma unroll
            for (int m = 0; m < 4; m++)
                #pragma unroll
                for (int i2 = 0; i2 < 4; i2++) sc[m][i2] += dot4(Q[m], K4[i2]);
        }
        #pragma unroll
        for (int m = 0; m < 4; m++)
            #pragma unroll
            for (int i2 = 0; i2 < 4; i2++)
                s[(v0 + 16 * m) * 132 + l0 + 32 * i2] = sc[m][i2] * 0.25f;
    }
    __syncthreads();

    {   // softmax over 128
        int v = t >> 3, j = t & 7;
        float* sr = s + v * 132;
        float m = -1e30f;
        for (int k = j; k < NL; k += 8) m = fmaxf(m, sr[k]);
        for (int off = 1; off < 8; off <<= 1) m = fmaxf(m, __shfl_xor(m, off));
        float sum = 0.f;
        for (int k = j; k < NL; k += 8) { float e = __expf(sr[k] - m); sr[k] = e; sum += e; }
        for (int off = 1; off < 8; off <<= 1) sum += __shfl_xor(sum, off);
        if (j == 0) rsum[v] = sum;
    }
    __syncthreads();

    if (t < 256) {   // PV over 128
        int v = t >> 2, d0 = (t & 3) * 4;
        float o4[4] = {};
        for (int ll = 0; ll < NL; ll += 4) {
            f4 S4 = *(const f4*)&s[v * 132 + ll];
            #pragma unroll
            for (int i2 = 0; i2 < 4; i2++)
                o4[i2] += dot4(S4, *(const f4*)&vhT[(d0 + i2) * 132 + ll]);
        }
        float* ob = ws + OFF_OSA1 + b * 8192 + h * 16;   // osa1 dead, reuse
        float inv = 1.0f / rsum[v];
        #pragma unroll
        for (int i2 = 0; i2 < 4; i2++) ob[v * F + d0 + i2] = o4[i2] * inv;
    }
}

// ---------------- K4: output head + activation + broadcast, 8 bv per block ----------------
__global__ __launch_bounds__(512) void k4_out(InPtrs ptrs, float* __restrict__ ws,
                                              void* __restrict__ out) {
    int bid = blockIdx.x, t = threadIdx.x;
    int fl = detect_f32(ptrs.p[1], t);
    __shared__ float sm[4416];
    const float* ola  = ws + OFF_OSA1;
    const float* feat = ws + OFF_FEAT2;
    int bvl = t >> 6, tt = t & 63;
    int bv = bid * 8 + bvl;
    float* orow = sm + bvl * 128;
    float* h3   = sm + 1024 + bvl * 128;
    float* z1   = sm + 2048 + bvl * 128;
    float* z2   = sm + 3072 + bvl * 128;
    float* z3all = sm + 4096;               // [8][40]
    float* z3   = z3all + bvl * 40;
    orow[tt] = ola[bv * 128 + tt];
    orow[tt + 64] = ola[bv * 128 + tt + 64];
    __syncthreads();
    const float* wclaT = ws + WCLA_T;
    float a0 = 0.f, a1 = 0.f;
    for (int k = 0; k < 128; k++) {
        float x = orow[k];
        a0 += x * wclaT[k * 128 + tt]; a1 += x * wclaT[k * 128 + tt + 64];
    }
    h3[tt] = a0 + feat[bv * 128 + tt];
    h3[tt + 64] = a1 + feat[bv * 128 + tt + 64];
    __syncthreads();
    const float* w1T = ws + W1_T;
    a0 = ws[OFF_B1 + tt]; a1 = ws[OFF_B1 + tt + 64];
    for (int k = 0; k < 128; k++) {
        float x = h3[k];
        a0 += x * w1T[k * 128 + tt]; a1 += x * w1T[k * 128 + tt + 64];
    }
    z1[tt] = fmaxf(a0, 0.f); z1[tt + 64] = fmaxf(a1, 0.f);
    __syncthreads();
    const float* w2T = ws + W2_T;
    a0 = ws[OFF_B2 + tt]; a1 = ws[OFF_B2 + tt + 64];
    for (int k = 0; k < 128; k++) {
        float x = z1[k];
        a0 += x * w2T[k * 128 + tt]; a1 += x * w2T[k * 128 + tt + 64];
    }
    z2[tt] = fmaxf(a0, 0.f); z2[tt + 64] = fmaxf(a1, 0.f);
    __syncthreads();
    const float* woT = ws + WO_T;
    if (tt < 36) {
        float a = ws[OFF_BO + tt];
        for (int k = 0; k < 128; k++) a += z2[k] * woT[k * 36 + tt];
        z3[tt] = a;
    }
    __syncthreads();
    float r = 0.f;
    if (tt < 36) {
        int c = tt % 6;
        float xv = z3[tt];
        if (c == 0)      r = xv + ldin(ptrs.p[2], bv * 2 + 0, fl);
        else if (c == 1) r = xv + ldin(ptrs.p[2], bv * 2 + 1, fl);
        else if (c == 2 || c == 3) r = __expf(0.5f * xv);
        else if (c == 4) r = tanhf(xv);
        else {
            const float inv = 0.4082482904638631f;  // 1/sqrt(6)
            float m = -1e30f;
            for (int pp = 0; pp < 6; pp++) m = fmaxf(m, z3[pp * 6 + 5] * inv);
            float sum = 0.f;
            for (int pp = 0; pp < 6; pp++) sum += __expf(z3[pp * 6 + 5] * inv - m);
            r = __expf(xv * inv - m) / sum;
        }
    }
    __syncthreads();
    if (tt < 36) z3[tt] = r;
    __syncthreads();
    int base = bid * 288;
    if (fl) {
        float* o = (float*)out;
        for (int i = t; i < LEN_PRED * 288; i += 512) {
            int ttp = i / 288, idx = i - ttp * 288;
            o[ttp * 73728 + base + idx] = z3all[(idx / 36) * 40 + idx % 36];
        }
    } else {
        bf16* o = (bf16*)out;
        for (int i = t; i < LEN_PRED * 288; i += 512) {
            int ttp = i / 288, idx = i - ttp * 288;
            o[ttp * 73728 + base + idx] = __float2bfloat16(z3all[(idx / 36) * 40 + idx % 36]);
        }
    }
}

extern "C" void kernel_launch(void* const* d_in, const int* in_sizes, int n_in,
                              void* d_out, int out_size, void* d_ws, size_t ws_size,
                              hipStream_t stream) {
    float* ws = (float*)d_ws;
    InPtrs ptrs;
    for (int i = 0; i < 23; i++) ptrs.p[i] = d_in[i];
    k1_lap<<<256, 512, 0, stream>>>(ptrs, ws);
    k2_saf<<<256, 512, 0, stream>>>(ptrs, ws);
    k3_laf<<<256, 512, 0, stream>>>(ptrs, ws);
    k4_out<<<256, 512, 0, stream>>>(ptrs, ws, d_out);
}